// Round 5
// baseline (14049.220 us; speedup 1.0000x reference)
//
#include <hip/hip_runtime.h>
#include <hip/hip_bf16.h>

// SpatioTemporalGNN: B=16, N=500, T=256, F_IN=8, H=64, K=3, OUT=1
// (rev 5 — identical algorithm to rev 4; resubmitted after broker-side
//  UnresponsiveContainer failures in rounds 2-4 on a dead pod.)
// Pipeline (fused stages, intermediates bf16 in ws), chunked over batch to
// fit whatever ws_size the harness provides (>= ~33 MB needed for chunk=1):
//   k1: conv1(T)+bias+relu+support1        x(b,N,T,F) -> bufA (nb*H,N,T)
//   k2: adj-GEMM + gcn_b + relu + BN       bufA -> bufB
//   k3: conv2(T)+bias+relu+support2        bufB -> bufA
//   k4: adj-GEMM + gcn_b + relu + BN       bufA -> bufB
//   k5: mean over T + MLP(64->32->1)       bufB -> d_out (float)
// All static LDS kept < 64 KB (conv tiles staged as bf16).

#define BB 16
#define NN 500
#define TT 256
#define FIN 8
#define HH 64

using bf16 = __hip_bfloat16;

// ---------------- kernel 1: conv1 + relu + support1 ----------------
// one block per (n, lb); 256 threads; t = tid
__global__ __launch_bounds__(256) void k_conv_support1(
    const float* __restrict__ x, const float* __restrict__ cw,
    const float* __restrict__ cb, const float* __restrict__ gw,
    bf16* __restrict__ s_out)
{
    __shared__ __align__(16) float xs[258 * 8]; // padded x slice (t=-1..256, f=0..7)  8.25 KB
    __shared__ bf16 co[64 * 256];               // conv output (c, t)                  32 KB

    const int n = blockIdx.x, lb = blockIdx.y, tid = threadIdx.x;
    const float* base = x + (size_t)(lb * NN + n) * (TT * FIN);

    // stage x slice (2048 contiguous floats) + zero halo
    {
        const float4* b4 = (const float4*)base;
        float4* x4 = (float4*)(xs + 8);
        for (int i = tid; i < 512; i += 256) x4[i] = b4[i];
        if (tid < 8) xs[tid] = 0.f;
        if (tid >= 248) xs[1808 + tid] = 0.f;   // xs[2056..2063]
    }
    __syncthreads();

    const int t = tid;
    float4 xv[6];
    {
        const float4* xsv = (const float4*)xs;
        #pragma unroll
        for (int k = 0; k < 3; k++) { xv[2 * k] = xsv[(t + k) * 2]; xv[2 * k + 1] = xsv[(t + k) * 2 + 1]; }
    }
    // conv: each thread computes all 64 channels for its t
    for (int c = 0; c < 64; c++) {
        const float* wc = cw + c * 24;   // (c, f, k) contiguous, uniform -> s_loads
        float a = cb[c];
        #pragma unroll
        for (int k = 0; k < 3; k++) {
            float4 v0 = xv[2 * k], v1 = xv[2 * k + 1];
            a += v0.x * wc[k]      + v0.y * wc[3 + k]  + v0.z * wc[6 + k]  + v0.w * wc[9 + k]
               + v1.x * wc[12 + k] + v1.y * wc[15 + k] + v1.z * wc[18 + k] + v1.w * wc[21 + k];
        }
        co[c * 256 + t] = __float2bfloat16(fmaxf(a, 0.f));
    }
    __syncthreads();

    // support: acc[h] = sum_c co[c][t] * gw[c][h]
    float acc[64];
    #pragma unroll
    for (int h = 0; h < 64; h++) acc[h] = 0.f;
    for (int c = 0; c < 64; c++) {
        float rv = __bfloat162float(co[c * 256 + t]);
        const float* g = gw + c * 64;
        #pragma unroll
        for (int h = 0; h < 64; h++) acc[h] += rv * g[h];
    }
    size_t ob = (size_t)lb * 64 * (NN * TT) + (size_t)n * TT + t;
    #pragma unroll
    for (int h = 0; h < 64; h++)
        s_out[ob + (size_t)h * (NN * TT)] = __float2bfloat16(acc[h]);
}

// ---------------- kernel 2/4: adj GEMM + bias + relu + BN ----------------
// out[bh, m, t] = BN(relu(sum_n adj[m,n] * s[bh, n, t] + gb[h]))
// block: 64 m-rows x 256 t-cols for one (lb,h); grid (8, nb*64)
__global__ __launch_bounds__(256) void k_adj_bn(
    const bf16* __restrict__ s_in, const float* __restrict__ adj,
    const float* __restrict__ gb, const float* __restrict__ bn_g,
    const float* __restrict__ bn_b, const float* __restrict__ bn_m,
    const float* __restrict__ bn_v, bf16* __restrict__ h_out)
{
    const int t = threadIdx.x;
    const int m0 = blockIdx.x * 64;
    const int bh = blockIdx.y;
    const int h = bh & 63;

    float acc[64];
    #pragma unroll
    for (int m = 0; m < 64; m++) acc[m] = 0.f;

    const bf16* sp = s_in + (size_t)bh * (NN * TT) + t;
    for (int n0 = 0; n0 < NN; n0 += 20) {      // 500 = 25 * 20, uniform chunks
        float sreg[20];
        #pragma unroll
        for (int j = 0; j < 20; j++) sreg[j] = __bfloat162float(sp[(size_t)(n0 + j) * TT]);
        #pragma unroll
        for (int m = 0; m < 64; m++) {
            int row = m0 + m; row = row < NN ? row : NN - 1;   // clamp: keep loop static
            const float* ar = adj + row * NN + n0;             // uniform -> s_load_dwordx4
            float p = 0.f;
            #pragma unroll
            for (int j = 0; j < 20; j++) p += ar[j] * sreg[j];
            acc[m] += p;
        }
    }
    const float bias  = gb[h];
    const float scale = bn_g[h] / sqrtf(bn_v[h] + 1e-5f);
    const float shift = bn_b[h] - bn_m[h] * scale;
    const int mmax = (NN - m0) < 64 ? (NN - m0) : 64;
    for (int m = 0; m < mmax; m++) {
        float v = fmaxf(acc[m] + bias, 0.f);
        h_out[((size_t)bh * NN + (m0 + m)) * TT + t] = __float2bfloat16(v * scale + shift);
    }
}

// ---------------- transpose conv_w2 to [k][cin][cout] ----------------
__global__ __launch_bounds__(256) void k_transpose_w2(
    const float* __restrict__ w2, float* __restrict__ wT)
{
    int i = blockIdx.x * 256 + threadIdx.x;
    if (i < 64 * 64 * 3) {
        int k = i % 3; int cin = (i / 3) % 64; int c = i / 192;
        wT[(k * 64 + cin) * 64 + c] = w2[i];
    }
}

// ---------------- kernel 3: conv2 + relu + support2 ----------------
// block per (t-tile of 128, n, lb); 256 threads = (t 0..127) x (cout-half 0..1)
__global__ __launch_bounds__(256) void k_conv_support2(
    const bf16* __restrict__ hin, const float* __restrict__ wT,
    const float* __restrict__ cb, const float* __restrict__ gw,
    bf16* __restrict__ s_out)
{
    __shared__ float xs[64 * 130];   // (cin, t-1..t+128) fp32   33.3 KB
    __shared__ bf16  co[64 * 128];   // conv out (cout, t)       16 KB

    const int tid = threadIdx.x;
    const int t0 = blockIdx.x * 128;
    const int n = blockIdx.y;
    const int lb = blockIdx.z;
    const bf16* base = hin + ((size_t)lb * 64 * NN + n) * TT;   // + c*(NN*TT) + t

    for (int i = tid; i < 8192; i += 256) {
        int c = i >> 7, tt = i & 127;
        xs[c * 130 + 1 + tt] = __bfloat162float(base[(size_t)c * (NN * TT) + t0 + tt]);
    }
    if (tid < 64) {
        int c = tid;
        xs[c * 130] = (t0 > 0) ? __bfloat162float(base[(size_t)c * (NN * TT) + t0 - 1]) : 0.f;
    } else if (tid < 128) {
        int c = tid - 64;
        xs[c * 130 + 129] = (t0 + 128 < TT) ? __bfloat162float(base[(size_t)c * (NN * TT) + t0 + 128]) : 0.f;
    }
    __syncthreads();

    const int t = tid & 127;
    const int hf = tid >> 7;       // wave-uniform (tid 0..127 -> 0, 128..255 -> 1)

    float acc[32];
    {
        const float* cbh = cb + hf * 32;
        #pragma unroll
        for (int j = 0; j < 32; j++) acc[j] = cbh[j];
    }
    for (int cin = 0; cin < 64; cin++) {
        float x0 = xs[cin * 130 + t], x1 = xs[cin * 130 + t + 1], x2 = xs[cin * 130 + t + 2];
        const float* wa = wT + (0 * 64 + cin) * 64 + hf * 32;   // contiguous 32 -> s_loads
        const float* wb = wT + (1 * 64 + cin) * 64 + hf * 32;
        const float* wc = wT + (2 * 64 + cin) * 64 + hf * 32;
        #pragma unroll
        for (int j = 0; j < 32; j++) acc[j] += x0 * wa[j] + x1 * wb[j] + x2 * wc[j];
    }
    #pragma unroll
    for (int j = 0; j < 32; j++) co[(hf * 32 + j) * 128 + t] = __float2bfloat16(fmaxf(acc[j], 0.f));
    __syncthreads();

    float acc2[32];
    #pragma unroll
    for (int j = 0; j < 32; j++) acc2[j] = 0.f;
    for (int c = 0; c < 64; c++) {
        float rv = __bfloat162float(co[c * 128 + t]);
        const float* g = gw + c * 64 + hf * 32;
        #pragma unroll
        for (int j = 0; j < 32; j++) acc2[j] += rv * g[j];
    }
    size_t ob = ((size_t)(lb * 64 + hf * 32) * NN + n) * TT + t0 + t;
    #pragma unroll
    for (int j = 0; j < 32; j++)
        s_out[ob + (size_t)j * (NN * TT)] = __float2bfloat16(acc2[j]);
}

// ---------------- kernel 5: mean over T + MLP ----------------
__global__ __launch_bounds__(256) void k_mean_mlp(
    const bf16* __restrict__ hin, const float* __restrict__ w1,
    const float* __restrict__ b1, const float* __restrict__ w2,
    const float* __restrict__ b2, float* __restrict__ out)
{
    __shared__ bf16 sm[64 * 257];    // 33 KB
    __shared__ float mm[64];
    __shared__ float hid[32];
    const int n = blockIdx.x, lb = blockIdx.y, tid = threadIdx.x;

    for (int i = tid; i < 16384; i += 256) {
        int c = i >> 8, t = i & 255;
        sm[c * 257 + t] = hin[((size_t)(lb * 64 + c) * NN + n) * TT + t];
    }
    __syncthreads();
    if (tid < 64) {
        float s = 0.f;
        for (int t = 0; t < 256; t++) s += __bfloat162float(sm[tid * 257 + t]);
        mm[tid] = s * (1.f / 256.f);
    }
    __syncthreads();
    if (tid < 32) {
        float a = b1[tid];
        for (int c = 0; c < 64; c++) a += mm[c] * w1[c * 32 + tid];
        hid[tid] = fmaxf(a, 0.f);
    }
    __syncthreads();
    if (tid == 0) {
        float a = b2[0];
        for (int j = 0; j < 32; j++) a += hid[j] * w2[j];
        out[lb * NN + n] = a;
    }
}

extern "C" void kernel_launch(void* const* d_in, const int* in_sizes, int n_in,
                              void* d_out, int out_size, void* d_ws, size_t ws_size,
                              hipStream_t stream) {
    const float* x       = (const float*)d_in[0];
    const float* adj     = (const float*)d_in[1];
    const float* conv_w1 = (const float*)d_in[2];
    const float* conv_b1 = (const float*)d_in[3];
    const float* conv_w2 = (const float*)d_in[4];
    const float* conv_b2 = (const float*)d_in[5];
    const float* gcn_w1  = (const float*)d_in[6];
    const float* gcn_b1  = (const float*)d_in[7];
    const float* gcn_w2  = (const float*)d_in[8];
    const float* gcn_b2  = (const float*)d_in[9];
    const float* bn_g1   = (const float*)d_in[10];
    const float* bn_be1  = (const float*)d_in[11];
    const float* bn_m1   = (const float*)d_in[12];
    const float* bn_v1   = (const float*)d_in[13];
    const float* bn_g2   = (const float*)d_in[14];
    const float* bn_be2  = (const float*)d_in[15];
    const float* bn_m2   = (const float*)d_in[16];
    const float* bn_v2   = (const float*)d_in[17];
    const float* out_w1  = (const float*)d_in[18];
    const float* out_b1  = (const float*)d_in[19];
    const float* out_w2  = (const float*)d_in[20];
    const float* out_b2  = (const float*)d_in[21];
    float* out = (float*)d_out;

    const size_t per_b = (size_t)HH * NN * TT;             // 8,192,000 elems per batch
    // ws layout: [wT: 64 KB][bufA: chunk*per_b*2][bufB: chunk*per_b*2]
    const size_t bytes_per_b_both = per_b * 2 * 2;         // 32,768,000 B
    int chunk = (int)((ws_size > 65536 ? ws_size - 65536 : 0) / bytes_per_b_both);
    if (chunk > BB) chunk = BB;
    if (chunk < 1) chunk = 1;   // last resort; needs ~33 MB ws

    char* ws = (char*)d_ws;
    float* wT  = (float*)ws;                               // 49,152 B used
    bf16* bufA = (bf16*)(ws + 65536);
    bf16* bufB = bufA + (size_t)chunk * per_b;

    k_transpose_w2<<<48, 256, 0, stream>>>(conv_w2, wT);

    for (int b0 = 0; b0 < BB; b0 += chunk) {
        const int nb = (BB - b0) < chunk ? (BB - b0) : chunk;

        k_conv_support1<<<dim3(NN, nb), 256, 0, stream>>>(
            x + (size_t)b0 * NN * TT * FIN, conv_w1, conv_b1, gcn_w1, bufA);

        k_adj_bn<<<dim3(8, nb * 64), 256, 0, stream>>>(
            bufA, adj, gcn_b1, bn_g1, bn_be1, bn_m1, bn_v1, bufB);

        k_conv_support2<<<dim3(2, NN, nb), 256, 0, stream>>>(
            bufB, wT, conv_b2, gcn_w2, bufA);

        k_adj_bn<<<dim3(8, nb * 64), 256, 0, stream>>>(
            bufA, adj, gcn_b2, bn_g2, bn_be2, bn_m2, bn_v2, bufB);

        k_mean_mlp<<<dim3(NN, nb), 256, 0, stream>>>(
            bufB, out_w1, out_b1, out_w2, out_b2, out + (size_t)b0 * NN);
    }
}

// Round 6
// 4595.673 us; speedup vs baseline: 3.0571x; 3.0571x over previous
//
#include <hip/hip_runtime.h>
#include <hip/hip_bf16.h>

// SpatioTemporalGNN: B=16, N=500, T=256, F_IN=8, H=64, K=3, OUT=1
// rev 6: k_adj_bn (scratch-spilled VALU loop, 49 TF) replaced by bf16-MFMA
// GEMM k_adj_mfma (adj pre-cast to padded bf16 [512][512]); k_mean_mlp mean
// made 4-way parallel. k1/k3 unchanged this round.
// ws: [adjb 512KB][wT 64KB @0x80000][bufA/bufB @0x100000, chunked over batch]

#define BB 16
#define NN 500
#define TT 256
#define FIN 8
#define HH 64

using bf16 = __hip_bfloat16;
typedef __attribute__((ext_vector_type(8))) short short8;
typedef __attribute__((ext_vector_type(4))) float f32x4;

// ---------------- kernel 1: conv1 + relu + support1 ----------------
__global__ __launch_bounds__(256) void k_conv_support1(
    const float* __restrict__ x, const float* __restrict__ cw,
    const float* __restrict__ cb, const float* __restrict__ gw,
    bf16* __restrict__ s_out)
{
    __shared__ __align__(16) float xs[258 * 8];
    __shared__ bf16 co[64 * 256];

    const int n = blockIdx.x, lb = blockIdx.y, tid = threadIdx.x;
    const float* base = x + (size_t)(lb * NN + n) * (TT * FIN);

    {
        const float4* b4 = (const float4*)base;
        float4* x4 = (float4*)(xs + 8);
        for (int i = tid; i < 512; i += 256) x4[i] = b4[i];
        if (tid < 8) xs[tid] = 0.f;
        if (tid >= 248) xs[1808 + tid] = 0.f;
    }
    __syncthreads();

    const int t = tid;
    float4 xv[6];
    {
        const float4* xsv = (const float4*)xs;
        #pragma unroll
        for (int k = 0; k < 3; k++) { xv[2 * k] = xsv[(t + k) * 2]; xv[2 * k + 1] = xsv[(t + k) * 2 + 1]; }
    }
    for (int c = 0; c < 64; c++) {
        const float* wc = cw + c * 24;
        float a = cb[c];
        #pragma unroll
        for (int k = 0; k < 3; k++) {
            float4 v0 = xv[2 * k], v1 = xv[2 * k + 1];
            a += v0.x * wc[k]      + v0.y * wc[3 + k]  + v0.z * wc[6 + k]  + v0.w * wc[9 + k]
               + v1.x * wc[12 + k] + v1.y * wc[15 + k] + v1.z * wc[18 + k] + v1.w * wc[21 + k];
        }
        co[c * 256 + t] = __float2bfloat16(fmaxf(a, 0.f));
    }
    __syncthreads();

    float acc[64];
    #pragma unroll
    for (int h = 0; h < 64; h++) acc[h] = 0.f;
    for (int c = 0; c < 64; c++) {
        float rv = __bfloat162float(co[c * 256 + t]);
        const float* g = gw + c * 64;
        #pragma unroll
        for (int h = 0; h < 64; h++) acc[h] += rv * g[h];
    }
    size_t ob = (size_t)lb * 64 * (NN * TT) + (size_t)n * TT + t;
    #pragma unroll
    for (int h = 0; h < 64; h++)
        s_out[ob + (size_t)h * (NN * TT)] = __float2bfloat16(acc[h]);
}

// ---------------- prep: adj (500x500 f32) -> adjb (512x512 bf16, zero-pad) ----------------
__global__ __launch_bounds__(256) void k_prep_adj(
    const float* __restrict__ adj, bf16* __restrict__ adjb)
{
    int i = blockIdx.x * 256 + threadIdx.x;
    if (i < 512 * 512) {
        int r = i >> 9, c = i & 511;
        float v = (r < NN && c < NN) ? adj[r * NN + c] : 0.f;
        adjb[i] = __float2bfloat16(v);
    }
}

// ---------------- kernel 2/4: adj GEMM via MFMA + bias + relu + BN ----------------
// C[m,t] = sum_n adj[m,n] * S[n,t] per (b,h) slice; K padded 500->512.
// grid (8, nb*64): bx>>1 = m-tile (128), bx&1 = t-tile (128). 4 waves 2x2,
// wave tile 64x64 = 4x4 MFMA 16x16x32 frags, acc statically indexed.
__global__ __launch_bounds__(256) void k_adj_mfma(
    const bf16* __restrict__ s_in, const bf16* __restrict__ adjb,
    const float* __restrict__ gb, const float* __restrict__ bn_g,
    const float* __restrict__ bn_b, const float* __restrict__ bn_m,
    const float* __restrict__ bn_v, bf16* __restrict__ h_out)
{
    __shared__ __align__(16) short AsS[128 * 40];   // A tile [m 128][k 32], pitch 40
    __shared__ __align__(16) short BsS[32 * 136];   // B tile [k 32][t 128], pitch 136

    const int tid = threadIdx.x;
    const int m0 = (blockIdx.x >> 1) * 128;
    const int t0 = (blockIdx.x & 1) * 128;
    const int bh = blockIdx.y;
    const int h = bh & 63;

    const int lane = tid & 63;
    const int lr = lane & 15;          // row/col-in-frag
    const int kg = lane >> 4;          // k-group 0..3
    const int w = tid >> 6;
    const int wr = w >> 1, wc = w & 1; // wave 2x2

    f32x4 acc[4][4];
    #pragma unroll
    for (int mi = 0; mi < 4; mi++)
        #pragma unroll
        for (int ti = 0; ti < 4; ti++)
            acc[mi][ti] = (f32x4){0.f, 0.f, 0.f, 0.f};

    // staging index maps (constant per thread)
    const int ar = tid >> 1, ah = (tid & 1) * 16;        // A: row, k-half
    const int bk = tid >> 3, bs = (tid & 7) * 16;        // B: k-row, t-seg
    const bf16* sbase = s_in + (size_t)bh * (NN * TT) + t0 + bs;

    for (int s = 0; s < 16; s++) {
        const int k0 = s * 32;
        // stage A: adjb[(m0+ar)][k0+ah .. +15] -> AsS[ar][ah..]
        {
            const float4* src = (const float4*)(adjb + (size_t)(m0 + ar) * 512 + k0 + ah);
            float4* dst = (float4*)(AsS + ar * 40 + ah);
            dst[0] = src[0]; dst[1] = src[1];
        }
        // stage B: s_in[bh][k0+bk][t0+bs .. +15] -> BsS[bk][bs..] (zero pad k>=500)
        {
            float4 v0, v1;
            const int kglob = k0 + bk;
            if (kglob < NN) {
                const float4* src = (const float4*)(sbase + (size_t)kglob * TT);
                v0 = src[0]; v1 = src[1];
            } else {
                v0 = make_float4(0.f, 0.f, 0.f, 0.f); v1 = v0;
            }
            float4* dst = (float4*)(BsS + bk * 136 + bs);
            dst[0] = v0; dst[1] = v1;
        }
        __syncthreads();

        short8 af[4];
        #pragma unroll
        for (int mi = 0; mi < 4; mi++)
            af[mi] = *(const short8*)(AsS + (wr * 64 + mi * 16 + lr) * 40 + kg * 8);
        #pragma unroll
        for (int ti = 0; ti < 4; ti++) {
            const short* bp = BsS + (kg * 8) * 136 + wc * 64 + ti * 16 + lr;
            short8 bfr;
            #pragma unroll
            for (int j = 0; j < 8; j++) bfr[j] = bp[j * 136];
            #pragma unroll
            for (int mi = 0; mi < 4; mi++)
                acc[mi][ti] = __builtin_amdgcn_mfma_f32_16x16x32_bf16(af[mi], bfr, acc[mi][ti], 0, 0, 0);
        }
        __syncthreads();
    }

    const float bias  = gb[h];
    const float scale = bn_g[h] / sqrtf(bn_v[h] + 1e-5f);
    const float shift = bn_b[h] - bn_m[h] * scale;

    // D mapping: col = lane&15, row = (lane>>4)*4 + reg
    #pragma unroll
    for (int mi = 0; mi < 4; mi++) {
        const int mbase = m0 + wr * 64 + mi * 16 + kg * 4;
        #pragma unroll
        for (int r = 0; r < 4; r++) {
            const int m = mbase + r;
            if (m < NN) {
                bf16* orow = h_out + ((size_t)bh * NN + m) * TT + t0 + wc * 64 + lr;
                #pragma unroll
                for (int ti = 0; ti < 4; ti++) {
                    float v = fmaxf(acc[mi][ti][r] + bias, 0.f);
                    orow[ti * 16] = __float2bfloat16(v * scale + shift);
                }
            }
        }
    }
}

// ---------------- transpose conv_w2 to [k][cin][cout] ----------------
__global__ __launch_bounds__(256) void k_transpose_w2(
    const float* __restrict__ w2, float* __restrict__ wT)
{
    int i = blockIdx.x * 256 + threadIdx.x;
    if (i < 64 * 64 * 3) {
        int k = i % 3; int cin = (i / 3) % 64; int c = i / 192;
        wT[(k * 64 + cin) * 64 + c] = w2[i];
    }
}

// ---------------- kernel 3: conv2 + relu + support2 ----------------
__global__ __launch_bounds__(256) void k_conv_support2(
    const bf16* __restrict__ hin, const float* __restrict__ wT,
    const float* __restrict__ cb, const float* __restrict__ gw,
    bf16* __restrict__ s_out)
{
    __shared__ float xs[64 * 130];
    __shared__ bf16  co[64 * 128];

    const int tid = threadIdx.x;
    const int t0 = blockIdx.x * 128;
    const int n = blockIdx.y;
    const int lb = blockIdx.z;
    const bf16* base = hin + ((size_t)lb * 64 * NN + n) * TT;

    for (int i = tid; i < 8192; i += 256) {
        int c = i >> 7, tt = i & 127;
        xs[c * 130 + 1 + tt] = __bfloat162float(base[(size_t)c * (NN * TT) + t0 + tt]);
    }
    if (tid < 64) {
        int c = tid;
        xs[c * 130] = (t0 > 0) ? __bfloat162float(base[(size_t)c * (NN * TT) + t0 - 1]) : 0.f;
    } else if (tid < 128) {
        int c = tid - 64;
        xs[c * 130 + 129] = (t0 + 128 < TT) ? __bfloat162float(base[(size_t)c * (NN * TT) + t0 + 128]) : 0.f;
    }
    __syncthreads();

    const int t = tid & 127;
    const int hf = tid >> 7;

    float acc[32];
    {
        const float* cbh = cb + hf * 32;
        #pragma unroll
        for (int j = 0; j < 32; j++) acc[j] = cbh[j];
    }
    for (int cin = 0; cin < 64; cin++) {
        float x0 = xs[cin * 130 + t], x1 = xs[cin * 130 + t + 1], x2 = xs[cin * 130 + t + 2];
        const float* wa = wT + (0 * 64 + cin) * 64 + hf * 32;
        const float* wb = wT + (1 * 64 + cin) * 64 + hf * 32;
        const float* wc = wT + (2 * 64 + cin) * 64 + hf * 32;
        #pragma unroll
        for (int j = 0; j < 32; j++) acc[j] += x0 * wa[j] + x1 * wb[j] + x2 * wc[j];
    }
    #pragma unroll
    for (int j = 0; j < 32; j++) co[(hf * 32 + j) * 128 + t] = __float2bfloat16(fmaxf(acc[j], 0.f));
    __syncthreads();

    float acc2[32];
    #pragma unroll
    for (int j = 0; j < 32; j++) acc2[j] = 0.f;
    for (int c = 0; c < 64; c++) {
        float rv = __bfloat162float(co[c * 128 + t]);
        const float* g = gw + c * 64 + hf * 32;
        #pragma unroll
        for (int j = 0; j < 32; j++) acc2[j] += rv * g[j];
    }
    size_t ob = ((size_t)(lb * 64 + hf * 32) * NN + n) * TT + t0 + t;
    #pragma unroll
    for (int j = 0; j < 32; j++)
        s_out[ob + (size_t)j * (NN * TT)] = __float2bfloat16(acc2[j]);
}

// ---------------- kernel 5: mean over T + MLP ----------------
__global__ __launch_bounds__(256) void k_mean_mlp(
    const bf16* __restrict__ hin, const float* __restrict__ w1,
    const float* __restrict__ b1, const float* __restrict__ w2,
    const float* __restrict__ b2, float* __restrict__ out)
{
    __shared__ bf16 sm[64 * 257];
    __shared__ float part[4][64];
    __shared__ float mm[64];
    __shared__ float hid[32];
    const int n = blockIdx.x, lb = blockIdx.y, tid = threadIdx.x;

    for (int i = tid; i < 16384; i += 256) {
        int c = i >> 8, t = i & 255;
        sm[c * 257 + t] = hin[((size_t)(lb * 64 + c) * NN + n) * TT + t];
    }
    __syncthreads();
    {
        const int c = tid & 63, q = tid >> 6;
        float s = 0.f;
        #pragma unroll 8
        for (int t = 0; t < 64; t++) s += __bfloat162float(sm[c * 257 + q * 64 + t]);
        part[q][c] = s;
    }
    __syncthreads();
    if (tid < 64)
        mm[tid] = (part[0][tid] + part[1][tid] + part[2][tid] + part[3][tid]) * (1.f / 256.f);
    __syncthreads();
    if (tid < 32) {
        float a = b1[tid];
        for (int c = 0; c < 64; c++) a += mm[c] * w1[c * 32 + tid];
        hid[tid] = fmaxf(a, 0.f);
    }
    __syncthreads();
    if (tid == 0) {
        float a = b2[0];
        for (int j = 0; j < 32; j++) a += hid[j] * w2[j];
        out[lb * NN + n] = a;
    }
}

extern "C" void kernel_launch(void* const* d_in, const int* in_sizes, int n_in,
                              void* d_out, int out_size, void* d_ws, size_t ws_size,
                              hipStream_t stream) {
    const float* x       = (const float*)d_in[0];
    const float* adj     = (const float*)d_in[1];
    const float* conv_w1 = (const float*)d_in[2];
    const float* conv_b1 = (const float*)d_in[3];
    const float* conv_w2 = (const float*)d_in[4];
    const float* conv_b2 = (const float*)d_in[5];
    const float* gcn_w1  = (const float*)d_in[6];
    const float* gcn_b1  = (const float*)d_in[7];
    const float* gcn_w2  = (const float*)d_in[8];
    const float* gcn_b2  = (const float*)d_in[9];
    const float* bn_g1   = (const float*)d_in[10];
    const float* bn_be1  = (const float*)d_in[11];
    const float* bn_m1   = (const float*)d_in[12];
    const float* bn_v1   = (const float*)d_in[13];
    const float* bn_g2   = (const float*)d_in[14];
    const float* bn_be2  = (const float*)d_in[15];
    const float* bn_m2   = (const float*)d_in[16];
    const float* bn_v2   = (const float*)d_in[17];
    const float* out_w1  = (const float*)d_in[18];
    const float* out_b1  = (const float*)d_in[19];
    const float* out_w2  = (const float*)d_in[20];
    const float* out_b2  = (const float*)d_in[21];
    float* out = (float*)d_out;

    const size_t per_b = (size_t)HH * NN * TT;             // 8,192,000 elems/batch
    const size_t reserve = 1 << 20;                        // adjb (512KB) + wT
    const size_t bytes_per_b_both = per_b * 2 * 2;         // 32,768,000 B
    int chunk = (int)((ws_size > reserve ? ws_size - reserve : 0) / bytes_per_b_both);
    if (chunk > BB) chunk = BB;
    if (chunk < 1) chunk = 1;

    char* ws = (char*)d_ws;
    bf16* adjb = (bf16*)ws;                                // 524,288 B
    float* wT  = (float*)(ws + 0x80000);                   // 49,152 B used
    bf16* bufA = (bf16*)(ws + reserve);
    bf16* bufB = bufA + (size_t)chunk * per_b;

    k_prep_adj<<<1024, 256, 0, stream>>>(adj, adjb);
    k_transpose_w2<<<48, 256, 0, stream>>>(conv_w2, wT);

    for (int b0 = 0; b0 < BB; b0 += chunk) {
        const int nb = (BB - b0) < chunk ? (BB - b0) : chunk;

        k_conv_support1<<<dim3(NN, nb), 256, 0, stream>>>(
            x + (size_t)b0 * NN * TT * FIN, conv_w1, conv_b1, gcn_w1, bufA);

        k_adj_mfma<<<dim3(8, nb * 64), 256, 0, stream>>>(
            bufA, adjb, gcn_b1, bn_g1, bn_be1, bn_m1, bn_v1, bufB);

        k_conv_support2<<<dim3(2, NN, nb), 256, 0, stream>>>(
            bufB, wT, conv_b2, gcn_w2, bufA);

        k_adj_mfma<<<dim3(8, nb * 64), 256, 0, stream>>>(
            bufA, adjb, gcn_b2, bn_g2, bn_be2, bn_m2, bn_v2, bufB);

        k_mean_mlp<<<dim3(NN, nb), 256, 0, stream>>>(
            bufB, out_w1, out_b1, out_w2, out_b2, out + (size_t)b0 * NN);
    }
}

// Round 7
// 1189.656 us; speedup vs baseline: 11.8095x; 3.8630x over previous
//
#include <hip/hip_runtime.h>
#include <hip/hip_bf16.h>

// SpatioTemporalGNN: B=16, N=500, T=256, F_IN=8, H=64, K=3, OUT=1
// rev 7: k_conv_support2 (latency-bound VALU, 35 TF eff) replaced by MFMA
// kernel k_conv_mfma2: conv2 as 3 shifted K=64 GEMMs + support2 GEMM, x
// staged transposed [t][cin] in LDS with XOR swizzle (both sides), phased
// LDS reuse for y. Weights pre-packed bf16 (wA[kk][cout][cin], gA[h][c]).
// k1 / k_adj_mfma / k_mean_mlp unchanged from rev 6.
// ws: [adjb 512KB][wA 24KB + gA 8KB @0x80000][bufA/bufB @1MB, chunked]

#define BB 16
#define NN 500
#define TT 256
#define FIN 8
#define HH 64

using bf16 = __hip_bfloat16;
typedef __attribute__((ext_vector_type(8))) short short8;
typedef __attribute__((ext_vector_type(4))) short short4v;
typedef __attribute__((ext_vector_type(4))) float f32x4;

static __device__ __forceinline__ short bf16bits(float v) {
    __hip_bfloat16 h = __float2bfloat16(v);
    return *reinterpret_cast<short*>(&h);
}

// ---------------- kernel 1: conv1 + relu + support1 ----------------
__global__ __launch_bounds__(256) void k_conv_support1(
    const float* __restrict__ x, const float* __restrict__ cw,
    const float* __restrict__ cb, const float* __restrict__ gw,
    bf16* __restrict__ s_out)
{
    __shared__ __align__(16) float xs[258 * 8];
    __shared__ bf16 co[64 * 256];

    const int n = blockIdx.x, lb = blockIdx.y, tid = threadIdx.x;
    const float* base = x + (size_t)(lb * NN + n) * (TT * FIN);

    {
        const float4* b4 = (const float4*)base;
        float4* x4 = (float4*)(xs + 8);
        for (int i = tid; i < 512; i += 256) x4[i] = b4[i];
        if (tid < 8) xs[tid] = 0.f;
        if (tid >= 248) xs[1808 + tid] = 0.f;
    }
    __syncthreads();

    const int t = tid;
    float4 xv[6];
    {
        const float4* xsv = (const float4*)xs;
        #pragma unroll
        for (int k = 0; k < 3; k++) { xv[2 * k] = xsv[(t + k) * 2]; xv[2 * k + 1] = xsv[(t + k) * 2 + 1]; }
    }
    for (int c = 0; c < 64; c++) {
        const float* wc = cw + c * 24;
        float a = cb[c];
        #pragma unroll
        for (int k = 0; k < 3; k++) {
            float4 v0 = xv[2 * k], v1 = xv[2 * k + 1];
            a += v0.x * wc[k]      + v0.y * wc[3 + k]  + v0.z * wc[6 + k]  + v0.w * wc[9 + k]
               + v1.x * wc[12 + k] + v1.y * wc[15 + k] + v1.z * wc[18 + k] + v1.w * wc[21 + k];
        }
        co[c * 256 + t] = __float2bfloat16(fmaxf(a, 0.f));
    }
    __syncthreads();

    float acc[64];
    #pragma unroll
    for (int h = 0; h < 64; h++) acc[h] = 0.f;
    for (int c = 0; c < 64; c++) {
        float rv = __bfloat162float(co[c * 256 + t]);
        const float* g = gw + c * 64;
        #pragma unroll
        for (int h = 0; h < 64; h++) acc[h] += rv * g[h];
    }
    size_t ob = (size_t)lb * 64 * (NN * TT) + (size_t)n * TT + t;
    #pragma unroll
    for (int h = 0; h < 64; h++)
        s_out[ob + (size_t)h * (NN * TT)] = __float2bfloat16(acc[h]);
}

// ---------------- prep: adj -> padded bf16 [512][512] ----------------
__global__ __launch_bounds__(256) void k_prep_adj(
    const float* __restrict__ adj, bf16* __restrict__ adjb)
{
    int i = blockIdx.x * 256 + threadIdx.x;
    if (i < 512 * 512) {
        int r = i >> 9, c = i & 511;
        float v = (r < NN && c < NN) ? adj[r * NN + c] : 0.f;
        adjb[i] = __float2bfloat16(v);
    }
}

// ---------------- prep: pack conv_w2 / gcn_w2 to bf16 MFMA-A layouts ----------------
// wA[(kk*64+co)*64+ci] = w2[(co*64+ci)*3+kk]   (12288 elems)
// gA[h*64+c]           = gw2[c*64+h]           (4096 elems)
__global__ __launch_bounds__(256) void k_prep_w2(
    const float* __restrict__ w2, const float* __restrict__ gw2,
    bf16* __restrict__ wA, bf16* __restrict__ gA)
{
    int i = blockIdx.x * 256 + threadIdx.x;
    if (i < 12288) {
        int kk = i / 4096, r = i & 4095;
        int co = r >> 6, ci = r & 63;
        wA[i] = __float2bfloat16(w2[(co * 64 + ci) * 3 + kk]);
    } else if (i < 16384) {
        int r = i - 12288;
        int h = r >> 6, c = r & 63;
        gA[r] = __float2bfloat16(gw2[c * 64 + h]);
    }
}

// ---------------- kernel 2/4: adj GEMM via MFMA + bias + relu + BN ----------------
__global__ __launch_bounds__(256) void k_adj_mfma(
    const bf16* __restrict__ s_in, const bf16* __restrict__ adjb,
    const float* __restrict__ gb, const float* __restrict__ bn_g,
    const float* __restrict__ bn_b, const float* __restrict__ bn_m,
    const float* __restrict__ bn_v, bf16* __restrict__ h_out)
{
    __shared__ __align__(16) short AsS[128 * 40];
    __shared__ __align__(16) short BsS[32 * 136];

    const int tid = threadIdx.x;
    const int m0 = (blockIdx.x >> 1) * 128;
    const int t0 = (blockIdx.x & 1) * 128;
    const int bh = blockIdx.y;
    const int h = bh & 63;

    const int lane = tid & 63;
    const int lr = lane & 15;
    const int kg = lane >> 4;
    const int w = tid >> 6;
    const int wr = w >> 1, wc = w & 1;

    f32x4 acc[4][4];
    #pragma unroll
    for (int mi = 0; mi < 4; mi++)
        #pragma unroll
        for (int ti = 0; ti < 4; ti++)
            acc[mi][ti] = (f32x4){0.f, 0.f, 0.f, 0.f};

    const int ar = tid >> 1, ah = (tid & 1) * 16;
    const int bk = tid >> 3, bs = (tid & 7) * 16;
    const bf16* sbase = s_in + (size_t)bh * (NN * TT) + t0 + bs;

    for (int s = 0; s < 16; s++) {
        const int k0 = s * 32;
        {
            const float4* src = (const float4*)(adjb + (size_t)(m0 + ar) * 512 + k0 + ah);
            float4* dst = (float4*)(AsS + ar * 40 + ah);
            dst[0] = src[0]; dst[1] = src[1];
        }
        {
            float4 v0, v1;
            const int kglob = k0 + bk;
            if (kglob < NN) {
                const float4* src = (const float4*)(sbase + (size_t)kglob * TT);
                v0 = src[0]; v1 = src[1];
            } else {
                v0 = make_float4(0.f, 0.f, 0.f, 0.f); v1 = v0;
            }
            float4* dst = (float4*)(BsS + bk * 136 + bs);
            dst[0] = v0; dst[1] = v1;
        }
        __syncthreads();

        short8 af[4];
        #pragma unroll
        for (int mi = 0; mi < 4; mi++)
            af[mi] = *(const short8*)(AsS + (wr * 64 + mi * 16 + lr) * 40 + kg * 8);
        #pragma unroll
        for (int ti = 0; ti < 4; ti++) {
            const short* bp = BsS + (kg * 8) * 136 + wc * 64 + ti * 16 + lr;
            short8 bfr;
            #pragma unroll
            for (int j = 0; j < 8; j++) bfr[j] = bp[j * 136];
            #pragma unroll
            for (int mi = 0; mi < 4; mi++)
                acc[mi][ti] = __builtin_amdgcn_mfma_f32_16x16x32_bf16(af[mi], bfr, acc[mi][ti], 0, 0, 0);
        }
        __syncthreads();
    }

    const float bias  = gb[h];
    const float scale = bn_g[h] / sqrtf(bn_v[h] + 1e-5f);
    const float shift = bn_b[h] - bn_m[h] * scale;

    #pragma unroll
    for (int mi = 0; mi < 4; mi++) {
        const int mbase = m0 + wr * 64 + mi * 16 + kg * 4;
        #pragma unroll
        for (int r = 0; r < 4; r++) {
            const int m = mbase + r;
            if (m < NN) {
                bf16* orow = h_out + ((size_t)bh * NN + m) * TT + t0 + wc * 64 + lr;
                #pragma unroll
                for (int ti = 0; ti < 4; ti++) {
                    float v = fmaxf(acc[mi][ti][r] + bias, 0.f);
                    orow[ti * 16] = __float2bfloat16(v * scale + shift);
                }
            }
        }
    }
}

// ---------------- kernel 3: conv2 + relu + support2 via MFMA ----------------
// Per block: one (b,n). x slice [64 cin][256 t] staged transposed in LDS as
// [row=t+1 (0..257)][cin 64] bf16, pitch 128 B, XOR-swizzled (byte ^=
// (row&7)<<4). Conv = 3 shifted GEMMs (kk) x 2 ksteps; y = relu(conv+cb)
// overwrites same LDS as [t][cout]; support2 = gA(64x64) . y -> global.
__global__ __launch_bounds__(256) void k_conv_mfma2(
    const bf16* __restrict__ hin, const bf16* __restrict__ wA,
    const bf16* __restrict__ gA, const float* __restrict__ cb,
    bf16* __restrict__ s_out)
{
    __shared__ __align__(16) short xs[258 * 64];   // 33 KB, swizzled

    const int tid = threadIdx.x;
    const int n = blockIdx.x, lb = blockIdx.y;
    const int lane = tid & 63, w = tid >> 6;
    const int lr = lane & 15, kg = lane >> 4;
    const int t0w = w * 64;

    const bf16* base = hin + ((size_t)lb * 64 * NN + n) * TT;

    // ---- stage x transposed + swizzled ----
    {
        const int cin = tid >> 2, tq = (tid & 3) * 64;
        const short* gsrc = (const short*)(base + (size_t)cin * (NN * TT) + tq);
        #pragma unroll
        for (int i = 0; i < 8; i++) {
            short8 v = *(const short8*)(gsrc + i * 8);
            #pragma unroll
            for (int j = 0; j < 8; j++) {
                const int row = tq + i * 8 + j + 1;
                const int addr = row * 128 + ((cin * 2) ^ ((row & 7) << 4));
                *(short*)((char*)xs + addr) = v[j];
            }
        }
        if (tid < 64) {                                   // halo rows t=-1, t=256
            *(short*)((char*)xs + (tid * 2)) = 0;                    // row 0, swz 0
            *(short*)((char*)xs + 257 * 128 + ((tid * 2) ^ 16)) = 0; // row 257, swz 16
        }
    }
    __syncthreads();

    // ---- conv: y[cout,t] = sum_{kk,cin} wA[kk][cout][cin] * x[cin][t+kk-1] ----
    f32x4 acc[4][4];
    #pragma unroll
    for (int mi = 0; mi < 4; mi++)
        #pragma unroll
        for (int ti = 0; ti < 4; ti++)
            acc[mi][ti] = (f32x4){0.f, 0.f, 0.f, 0.f};

    const short* wAp = (const short*)wA;
    #pragma unroll
    for (int kk = 0; kk < 3; kk++) {
        #pragma unroll
        for (int ks = 0; ks < 2; ks++) {
            short8 af[4], bfr[4];
            #pragma unroll
            for (int mi = 0; mi < 4; mi++)
                af[mi] = *(const short8*)(wAp + ((kk * 64 + mi * 16 + lr) * 64 + ks * 32 + kg * 8));
            #pragma unroll
            for (int ti = 0; ti < 4; ti++) {
                const int row = t0w + ti * 16 + lr + kk;      // = t_eff + 1
                const int addr = row * 128 + ((ks * 64 + kg * 16) ^ ((row & 7) << 4));
                bfr[ti] = *(const short8*)((const char*)xs + addr);
            }
            #pragma unroll
            for (int ti = 0; ti < 4; ti++)
                #pragma unroll
                for (int mi = 0; mi < 4; mi++)
                    acc[mi][ti] = __builtin_amdgcn_mfma_f32_16x16x32_bf16(af[mi], bfr[ti], acc[mi][ti], 0, 0, 0);
        }
    }
    __syncthreads();   // all conv reads done before overwriting LDS with y

    // ---- bias + relu, write y transposed [t][cout] into same LDS ----
    {
        float cbl[16];
        #pragma unroll
        for (int mi = 0; mi < 4; mi++)
            #pragma unroll
            for (int r = 0; r < 4; r++) cbl[mi * 4 + r] = cb[mi * 16 + kg * 4 + r];
        #pragma unroll
        for (int mi = 0; mi < 4; mi++) {
            #pragma unroll
            for (int ti = 0; ti < 4; ti++) {
                const int t = t0w + ti * 16 + lr;
                short4v yv;
                #pragma unroll
                for (int r = 0; r < 4; r++)
                    yv[r] = bf16bits(fmaxf(acc[mi][ti][r] + cbl[mi * 4 + r], 0.f));
                const int addr = t * 128 + ((mi * 32 + kg * 8) ^ ((t & 7) << 4));
                *(short4v*)((char*)xs + addr) = yv;
            }
        }
    }
    __syncthreads();

    // ---- support: s[h,t] = sum_c gA[h][c] * y[c][t] ----
    f32x4 acc2[4][4];
    #pragma unroll
    for (int mi = 0; mi < 4; mi++)
        #pragma unroll
        for (int ti = 0; ti < 4; ti++)
            acc2[mi][ti] = (f32x4){0.f, 0.f, 0.f, 0.f};

    const short* gAp = (const short*)gA;
    #pragma unroll
    for (int ks = 0; ks < 2; ks++) {
        short8 af[4], bfr[4];
        #pragma unroll
        for (int mi = 0; mi < 4; mi++)
            af[mi] = *(const short8*)(gAp + ((mi * 16 + lr) * 64 + ks * 32 + kg * 8));
        #pragma unroll
        for (int ti = 0; ti < 4; ti++) {
            const int t = t0w + ti * 16 + lr;
            const int addr = t * 128 + ((ks * 64 + kg * 16) ^ ((t & 7) << 4));
            bfr[ti] = *(const short8*)((const char*)xs + addr);
        }
        #pragma unroll
        for (int ti = 0; ti < 4; ti++)
            #pragma unroll
            for (int mi = 0; mi < 4; mi++)
                acc2[mi][ti] = __builtin_amdgcn_mfma_f32_16x16x32_bf16(af[mi], bfr[ti], acc2[mi][ti], 0, 0, 0);
    }

    // ---- epilogue: s_out[(lb*64+h)*NN + n][t] ----
    #pragma unroll
    for (int mi = 0; mi < 4; mi++) {
        #pragma unroll
        for (int r = 0; r < 4; r++) {
            const int h = mi * 16 + kg * 4 + r;
            bf16* orow = s_out + ((size_t)(lb * 64 + h) * NN + n) * TT + t0w + lr;
            #pragma unroll
            for (int ti = 0; ti < 4; ti++)
                orow[ti * 16] = __float2bfloat16(acc2[mi][ti][r]);
        }
    }
}

// ---------------- kernel 5: mean over T + MLP ----------------
__global__ __launch_bounds__(256) void k_mean_mlp(
    const bf16* __restrict__ hin, const float* __restrict__ w1,
    const float* __restrict__ b1, const float* __restrict__ w2,
    const float* __restrict__ b2, float* __restrict__ out)
{
    __shared__ bf16 sm[64 * 257];
    __shared__ float part[4][64];
    __shared__ float mm[64];
    __shared__ float hid[32];
    const int n = blockIdx.x, lb = blockIdx.y, tid = threadIdx.x;

    for (int i = tid; i < 16384; i += 256) {
        int c = i >> 8, t = i & 255;
        sm[c * 257 + t] = hin[((size_t)(lb * 64 + c) * NN + n) * TT + t];
    }
    __syncthreads();
    {
        const int c = tid & 63, q = tid >> 6;
        float s = 0.f;
        #pragma unroll 8
        for (int t = 0; t < 64; t++) s += __bfloat162float(sm[c * 257 + q * 64 + t]);
        part[q][c] = s;
    }
    __syncthreads();
    if (tid < 64)
        mm[tid] = (part[0][tid] + part[1][tid] + part[2][tid] + part[3][tid]) * (1.f / 256.f);
    __syncthreads();
    if (tid < 32) {
        float a = b1[tid];
        for (int c = 0; c < 64; c++) a += mm[c] * w1[c * 32 + tid];
        hid[tid] = fmaxf(a, 0.f);
    }
    __syncthreads();
    if (tid == 0) {
        float a = b2[0];
        for (int j = 0; j < 32; j++) a += hid[j] * w2[j];
        out[lb * NN + n] = a;
    }
}

extern "C" void kernel_launch(void* const* d_in, const int* in_sizes, int n_in,
                              void* d_out, int out_size, void* d_ws, size_t ws_size,
                              hipStream_t stream) {
    const float* x       = (const float*)d_in[0];
    const float* adj     = (const float*)d_in[1];
    const float* conv_w1 = (const float*)d_in[2];
    const float* conv_b1 = (const float*)d_in[3];
    const float* conv_w2 = (const float*)d_in[4];
    const float* conv_b2 = (const float*)d_in[5];
    const float* gcn_w1  = (const float*)d_in[6];
    const float* gcn_b1  = (const float*)d_in[7];
    const float* gcn_w2  = (const float*)d_in[8];
    const float* gcn_b2  = (const float*)d_in[9];
    const float* bn_g1   = (const float*)d_in[10];
    const float* bn_be1  = (const float*)d_in[11];
    const float* bn_m1   = (const float*)d_in[12];
    const float* bn_v1   = (const float*)d_in[13];
    const float* bn_g2   = (const float*)d_in[14];
    const float* bn_be2  = (const float*)d_in[15];
    const float* bn_m2   = (const float*)d_in[16];
    const float* bn_v2   = (const float*)d_in[17];
    const float* out_w1  = (const float*)d_in[18];
    const float* out_b1  = (const float*)d_in[19];
    const float* out_w2  = (const float*)d_in[20];
    const float* out_b2  = (const float*)d_in[21];
    float* out = (float*)d_out;

    const size_t per_b = (size_t)HH * NN * TT;             // 8,192,000 elems/batch
    const size_t reserve = 1 << 20;                        // adjb + packed weights
    const size_t bytes_per_b_both = per_b * 2 * 2;         // 32,768,000 B
    int chunk = (int)((ws_size > reserve ? ws_size - reserve : 0) / bytes_per_b_both);
    if (chunk > BB) chunk = BB;
    if (chunk < 1) chunk = 1;

    char* ws = (char*)d_ws;
    bf16* adjb = (bf16*)ws;                                // 524,288 B
    bf16* wA   = (bf16*)(ws + 0x80000);                    // 24,576 B
    bf16* gA   = (bf16*)(ws + 0x80000 + 24576);            // 8,192 B
    bf16* bufA = (bf16*)(ws + reserve);
    bf16* bufB = bufA + (size_t)chunk * per_b;

    k_prep_adj<<<1024, 256, 0, stream>>>(adj, adjb);
    k_prep_w2<<<64, 256, 0, stream>>>(conv_w2, gcn_w2, wA, gA);

    for (int b0 = 0; b0 < BB; b0 += chunk) {
        const int nb = (BB - b0) < chunk ? (BB - b0) : chunk;

        k_conv_support1<<<dim3(NN, nb), 256, 0, stream>>>(
            x + (size_t)b0 * NN * TT * FIN, conv_w1, conv_b1, gcn_w1, bufA);

        k_adj_mfma<<<dim3(8, nb * 64), 256, 0, stream>>>(
            bufA, adjb, gcn_b1, bn_g1, bn_be1, bn_m1, bn_v1, bufB);

        k_conv_mfma2<<<dim3(NN, nb), 256, 0, stream>>>(
            bufB, wA, gA, conv_b2, bufA);

        k_adj_mfma<<<dim3(8, nb * 64), 256, 0, stream>>>(
            bufA, adjb, gcn_b2, bn_g2, bn_be2, bn_m2, bn_v2, bufB);

        k_mean_mlp<<<dim3(NN, nb), 256, 0, stream>>>(
            bufB, out_w1, out_b1, out_w2, out_b2, out + (size_t)b0 * NN);
    }
}

// Round 8
// 878.158 us; speedup vs baseline: 15.9985x; 1.3547x over previous
//
#include <hip/hip_runtime.h>
#include <hip/hip_bf16.h>

// SpatioTemporalGNN: B=16, N=500, T=256, F_IN=8, H=64, K=3, OUT=1
// rev 8:
//  - k_conv_support1 (79% of fp32-VALU ceiling) -> k_conv_mfma1: conv1 as a
//    single K=32 MFMA step (k' = kk*8+f, zero-padded), B-tile built directly
//    from global x; then support1 GEMM. Structure cloned from proven
//    k_conv_mfma2 (same swizzle, same phased LDS reuse).
//  - k_adj_mfma templated <MEAN>: layer-2 variant skips the 131MB h_out
//    write; sums BN'd values over t in-register (shfl_xor over lr group) and
//    writes float4 partials pf[(tile*2+wc)][bh][m] into bufB's dead space.
//    k_mean_mlp (262MB re-read) -> tiny k_mlp over pf.
// ws: [adjb 512K][wA2/gA2/wA1/gA1 @0x80000][bufA/bufB @1MB; pf aliases bufB]

#define BB 16
#define NN 500
#define TT 256
#define FIN 8
#define HH 64

using bf16 = __hip_bfloat16;
typedef __attribute__((ext_vector_type(8))) short short8;
typedef __attribute__((ext_vector_type(4))) short short4v;
typedef __attribute__((ext_vector_type(4))) float f32x4;

static __device__ __forceinline__ short bf16bits(float v) {
    __hip_bfloat16 h = __float2bfloat16(v);
    return *reinterpret_cast<short*>(&h);
}

// ---------------- prep: adj -> padded bf16 [512][512] ----------------
__global__ __launch_bounds__(256) void k_prep_adj(
    const float* __restrict__ adj, bf16* __restrict__ adjb)
{
    int i = blockIdx.x * 256 + threadIdx.x;
    if (i < 512 * 512) {
        int r = i >> 9, c = i & 511;
        float v = (r < NN && c < NN) ? adj[r * NN + c] : 0.f;
        adjb[i] = __float2bfloat16(v);
    }
}

// ---------------- prep: pack all conv/gcn weights to bf16 MFMA-A layouts ----------------
// wA1[h*32 + kk*8+f] = cw1[(h*8+f)*3+kk] (kk<3 else 0)   [2048]
// gA1[h*64 + c]      = gw1[c*64+h]                        [4096]
// wA2[(kk*64+co)*64+ci] = w2[(co*64+ci)*3+kk]             [12288]
// gA2[h*64 + c]      = gw2[c*64+h]                        [4096]
__global__ __launch_bounds__(256) void k_prep_weights(
    const float* __restrict__ cw1, const float* __restrict__ gw1,
    const float* __restrict__ w2,  const float* __restrict__ gw2,
    bf16* __restrict__ wA1, bf16* __restrict__ gA1,
    bf16* __restrict__ wA2, bf16* __restrict__ gA2)
{
    int i = blockIdx.x * 256 + threadIdx.x;
    if (i < 2048) {
        int h = i >> 5, kp = i & 31, kk = kp >> 3, f = kp & 7;
        wA1[i] = __float2bfloat16(kk < 3 ? cw1[(h * 8 + f) * 3 + kk] : 0.f);
    } else if (i < 6144) {
        int j = i - 2048, h = j >> 6, c = j & 63;
        gA1[j] = __float2bfloat16(gw1[c * 64 + h]);
    } else if (i < 18432) {
        int j = i - 6144, kk = j / 4096, r = j & 4095, co = r >> 6, ci = r & 63;
        wA2[j] = __float2bfloat16(w2[(co * 64 + ci) * 3 + kk]);
    } else if (i < 22528) {
        int j = i - 18432, h = j >> 6, c = j & 63;
        gA2[j] = __float2bfloat16(gw2[c * 64 + h]);
    }
}

// ---------------- kernel 1: conv1 + relu + support1 via MFMA ----------------
// One block per (n, lb). B-tile [t 256][k' 32] built directly from x (k' =
// kk*8+f, x[t+kk-1][f]); conv = 1 k-step; y relu'd into same LDS [t][cout];
// support1 = gA1(64x64) . y -> bufA [bh][n][t].
__global__ __launch_bounds__(256) void k_conv_mfma1(
    const float* __restrict__ x, const bf16* __restrict__ wA1,
    const bf16* __restrict__ gA1, const float* __restrict__ cb,
    bf16* __restrict__ s_out)
{
    __shared__ __align__(16) short xs[256 * 64];   // 32 KB, pitch 128 B, swizzled

    const int tid = threadIdx.x;
    const int n = blockIdx.x, lb = blockIdx.y;
    const int lane = tid & 63, w = tid >> 6;
    const int lr = lane & 15, kg = lane >> 4;
    const int t0w = w * 64;

    // ---- build B-tile from global x (coalesced 32 B/thread) ----
    {
        const float4* gx = (const float4*)(x + (size_t)(lb * NN + n) * (TT * FIN) + tid * 8);
        float4 a = gx[0], b = gx[1];
        short8 v;
        v[0] = bf16bits(a.x); v[1] = bf16bits(a.y); v[2] = bf16bits(a.z); v[3] = bf16bits(a.w);
        v[4] = bf16bits(b.x); v[5] = bf16bits(b.y); v[6] = bf16bits(b.z); v[7] = bf16bits(b.w);
        const int t = tid;
        // kk=1 -> row t, slot 1 (bytes 16..31)
        *(short8*)((char*)xs + t * 128 + (16 ^ ((t & 7) << 4))) = v;
        // kk=0 -> row t+1, slot 0
        if (t < 255)
            *(short8*)((char*)xs + (t + 1) * 128 + (0 ^ (((t + 1) & 7) << 4))) = v;
        // kk=2 -> row t-1, slot 2 (bytes 32..47)
        if (t > 0)
            *(short8*)((char*)xs + (t - 1) * 128 + (32 ^ (((t - 1) & 7) << 4))) = v;
        // k' pad 24..31 -> slot 3 zero
        short8 z = {0, 0, 0, 0, 0, 0, 0, 0};
        *(short8*)((char*)xs + t * 128 + (48 ^ ((t & 7) << 4))) = z;
        // edge zeros: row 0 slot 0 (x[-1]), row 255 slot 2 (x[256])
        if (t == 0)   *(short8*)((char*)xs + 0 * 128 + (0 ^ 0)) = z;
        if (t == 255) *(short8*)((char*)xs + 255 * 128 + (32 ^ ((255 & 7) << 4))) = z;
    }
    __syncthreads();

    // ---- conv: y[cout,t] = sum_{k'} wA1[cout][k'] * B[k'][t] (one k-step) ----
    f32x4 acc[4][4];
    #pragma unroll
    for (int mi = 0; mi < 4; mi++)
        #pragma unroll
        for (int ti = 0; ti < 4; ti++)
            acc[mi][ti] = (f32x4){0.f, 0.f, 0.f, 0.f};

    const short* wAp = (const short*)wA1;
    {
        short8 af[4], bfr[4];
        #pragma unroll
        for (int mi = 0; mi < 4; mi++)
            af[mi] = *(const short8*)(wAp + (mi * 16 + lr) * 32 + kg * 8);
        #pragma unroll
        for (int ti = 0; ti < 4; ti++) {
            const int row = t0w + ti * 16 + lr;
            bfr[ti] = *(const short8*)((const char*)xs + row * 128 + ((kg * 16) ^ ((row & 7) << 4)));
        }
        #pragma unroll
        for (int ti = 0; ti < 4; ti++)
            #pragma unroll
            for (int mi = 0; mi < 4; mi++)
                acc[mi][ti] = __builtin_amdgcn_mfma_f32_16x16x32_bf16(af[mi], bfr[ti], acc[mi][ti], 0, 0, 0);
    }
    __syncthreads();   // conv reads done before overwriting LDS with y

    // ---- bias + relu, write y [t][cout] into same LDS ----
    {
        float cbl[16];
        #pragma unroll
        for (int mi = 0; mi < 4; mi++)
            #pragma unroll
            for (int r = 0; r < 4; r++) cbl[mi * 4 + r] = cb[mi * 16 + kg * 4 + r];
        #pragma unroll
        for (int mi = 0; mi < 4; mi++) {
            #pragma unroll
            for (int ti = 0; ti < 4; ti++) {
                const int t = t0w + ti * 16 + lr;
                short4v yv;
                #pragma unroll
                for (int r = 0; r < 4; r++)
                    yv[r] = bf16bits(fmaxf(acc[mi][ti][r] + cbl[mi * 4 + r], 0.f));
                *(short4v*)((char*)xs + t * 128 + ((mi * 32 + kg * 8) ^ ((t & 7) << 4))) = yv;
            }
        }
    }
    __syncthreads();

    // ---- support1: s[h,t] = sum_c gA1[h][c] * y[c][t] ----
    f32x4 acc2[4][4];
    #pragma unroll
    for (int mi = 0; mi < 4; mi++)
        #pragma unroll
        for (int ti = 0; ti < 4; ti++)
            acc2[mi][ti] = (f32x4){0.f, 0.f, 0.f, 0.f};

    const short* gAp = (const short*)gA1;
    #pragma unroll
    for (int ks = 0; ks < 2; ks++) {
        short8 af[4], bfr[4];
        #pragma unroll
        for (int mi = 0; mi < 4; mi++)
            af[mi] = *(const short8*)(gAp + (mi * 16 + lr) * 64 + ks * 32 + kg * 8);
        #pragma unroll
        for (int ti = 0; ti < 4; ti++) {
            const int t = t0w + ti * 16 + lr;
            bfr[ti] = *(const short8*)((const char*)xs + t * 128 + ((ks * 64 + kg * 16) ^ ((t & 7) << 4)));
        }
        #pragma unroll
        for (int ti = 0; ti < 4; ti++)
            #pragma unroll
            for (int mi = 0; mi < 4; mi++)
                acc2[mi][ti] = __builtin_amdgcn_mfma_f32_16x16x32_bf16(af[mi], bfr[ti], acc2[mi][ti], 0, 0, 0);
    }

    #pragma unroll
    for (int mi = 0; mi < 4; mi++) {
        #pragma unroll
        for (int r = 0; r < 4; r++) {
            const int h = mi * 16 + kg * 4 + r;
            bf16* orow = s_out + ((size_t)(lb * 64 + h) * NN + n) * TT + t0w + lr;
            #pragma unroll
            for (int ti = 0; ti < 4; ti++)
                orow[ti * 16] = __float2bfloat16(acc2[mi][ti][r]);
        }
    }
}

// ---------------- kernel 2/4: adj GEMM via MFMA + bias + relu + BN ----------------
// MEAN=false: write BN'd output to h_out [bh][m][t].
// MEAN=true: sum BN'd values over this wave's 64 t-cols, reduce over lr,
//            write float4 partials pf[(tile*2+wc)*gridDim.y*500 + bh*500 + m].
template<bool MEAN>
__global__ __launch_bounds__(256) void k_adj_mfma(
    const bf16* __restrict__ s_in, const bf16* __restrict__ adjb,
    const float* __restrict__ gb, const float* __restrict__ bn_g,
    const float* __restrict__ bn_b, const float* __restrict__ bn_m,
    const float* __restrict__ bn_v, bf16* __restrict__ h_out,
    float* __restrict__ pf)
{
    __shared__ __align__(16) short AsS[128 * 40];
    __shared__ __align__(16) short BsS[32 * 136];

    const int tid = threadIdx.x;
    const int m0 = (blockIdx.x >> 1) * 128;
    const int t0 = (blockIdx.x & 1) * 128;
    const int bh = blockIdx.y;
    const int h = bh & 63;

    const int lane = tid & 63;
    const int lr = lane & 15;
    const int kg = lane >> 4;
    const int w = tid >> 6;
    const int wr = w >> 1, wc = w & 1;

    f32x4 acc[4][4];
    #pragma unroll
    for (int mi = 0; mi < 4; mi++)
        #pragma unroll
        for (int ti = 0; ti < 4; ti++)
            acc[mi][ti] = (f32x4){0.f, 0.f, 0.f, 0.f};

    const int ar = tid >> 1, ah = (tid & 1) * 16;
    const int bk = tid >> 3, bs = (tid & 7) * 16;
    const bf16* sbase = s_in + (size_t)bh * (NN * TT) + t0 + bs;

    for (int s = 0; s < 16; s++) {
        const int k0 = s * 32;
        {
            const float4* src = (const float4*)(adjb + (size_t)(m0 + ar) * 512 + k0 + ah);
            float4* dst = (float4*)(AsS + ar * 40 + ah);
            dst[0] = src[0]; dst[1] = src[1];
        }
        {
            float4 v0, v1;
            const int kglob = k0 + bk;
            if (kglob < NN) {
                const float4* src = (const float4*)(sbase + (size_t)kglob * TT);
                v0 = src[0]; v1 = src[1];
            } else {
                v0 = make_float4(0.f, 0.f, 0.f, 0.f); v1 = v0;
            }
            float4* dst = (float4*)(BsS + bk * 136 + bs);
            dst[0] = v0; dst[1] = v1;
        }
        __syncthreads();

        short8 af[4];
        #pragma unroll
        for (int mi = 0; mi < 4; mi++)
            af[mi] = *(const short8*)(AsS + (wr * 64 + mi * 16 + lr) * 40 + kg * 8);
        #pragma unroll
        for (int ti = 0; ti < 4; ti++) {
            const short* bp = BsS + (kg * 8) * 136 + wc * 64 + ti * 16 + lr;
            short8 bfr;
            #pragma unroll
            for (int j = 0; j < 8; j++) bfr[j] = bp[j * 136];
            #pragma unroll
            for (int mi = 0; mi < 4; mi++)
                acc[mi][ti] = __builtin_amdgcn_mfma_f32_16x16x32_bf16(af[mi], bfr, acc[mi][ti], 0, 0, 0);
        }
        __syncthreads();
    }

    const float bias  = gb[h];
    const float scale = bn_g[h] / sqrtf(bn_v[h] + 1e-5f);
    const float shift = bn_b[h] - bn_m[h] * scale;

    if constexpr (!MEAN) {
        #pragma unroll
        for (int mi = 0; mi < 4; mi++) {
            const int mbase = m0 + wr * 64 + mi * 16 + kg * 4;
            #pragma unroll
            for (int r = 0; r < 4; r++) {
                const int m = mbase + r;
                if (m < NN) {
                    bf16* orow = h_out + ((size_t)bh * NN + m) * TT + t0 + wc * 64 + lr;
                    #pragma unroll
                    for (int ti = 0; ti < 4; ti++) {
                        float v = fmaxf(acc[mi][ti][r] + bias, 0.f);
                        orow[ti * 16] = __float2bfloat16(v * scale + shift);
                    }
                }
            }
        }
    } else {
        float sums[4][4];
        #pragma unroll
        for (int mi = 0; mi < 4; mi++)
            #pragma unroll
            for (int r = 0; r < 4; r++) {
                float s = 0.f;
                #pragma unroll
                for (int ti = 0; ti < 4; ti++)
                    s += fmaxf(acc[mi][ti][r] + bias, 0.f) * scale + shift;
                sums[mi][r] = s;
            }
        #pragma unroll
        for (int off = 1; off < 16; off <<= 1)
            #pragma unroll
            for (int mi = 0; mi < 4; mi++)
                #pragma unroll
                for (int r = 0; r < 4; r++)
                    sums[mi][r] += __shfl_xor(sums[mi][r], off, 64);
        if (lr == 0) {
            const size_t stride = (size_t)gridDim.y * NN;
            float* pfb = pf + ((size_t)((blockIdx.x & 1) * 2 + wc)) * stride + (size_t)bh * NN;
            #pragma unroll
            for (int mi = 0; mi < 4; mi++) {
                const int m = m0 + wr * 64 + mi * 16 + kg * 4;
                if (m < NN) {
                    float4 v = make_float4(sums[mi][0], sums[mi][1], sums[mi][2], sums[mi][3]);
                    *(float4*)(pfb + m) = v;
                }
            }
        }
    }
}

// ---------------- kernel 3: conv2 + relu + support2 via MFMA ----------------
__global__ __launch_bounds__(256) void k_conv_mfma2(
    const bf16* __restrict__ hin, const bf16* __restrict__ wA,
    const bf16* __restrict__ gA, const float* __restrict__ cb,
    bf16* __restrict__ s_out)
{
    __shared__ __align__(16) short xs[258 * 64];   // 33 KB, swizzled

    const int tid = threadIdx.x;
    const int n = blockIdx.x, lb = blockIdx.y;
    const int lane = tid & 63, w = tid >> 6;
    const int lr = lane & 15, kg = lane >> 4;
    const int t0w = w * 64;

    const bf16* base = hin + ((size_t)lb * 64 * NN + n) * TT;

    {
        const int cin = tid >> 2, tq = (tid & 3) * 64;
        const short* gsrc = (const short*)(base + (size_t)cin * (NN * TT) + tq);
        #pragma unroll
        for (int i = 0; i < 8; i++) {
            short8 v = *(const short8*)(gsrc + i * 8);
            #pragma unroll
            for (int j = 0; j < 8; j++) {
                const int row = tq + i * 8 + j + 1;
                const int addr = row * 128 + ((cin * 2) ^ ((row & 7) << 4));
                *(short*)((char*)xs + addr) = v[j];
            }
        }
        if (tid < 64) {
            *(short*)((char*)xs + (tid * 2)) = 0;
            *(short*)((char*)xs + 257 * 128 + ((tid * 2) ^ 16)) = 0;
        }
    }
    __syncthreads();

    f32x4 acc[4][4];
    #pragma unroll
    for (int mi = 0; mi < 4; mi++)
        #pragma unroll
        for (int ti = 0; ti < 4; ti++)
            acc[mi][ti] = (f32x4){0.f, 0.f, 0.f, 0.f};

    const short* wAp = (const short*)wA;
    #pragma unroll
    for (int kk = 0; kk < 3; kk++) {
        #pragma unroll
        for (int ks = 0; ks < 2; ks++) {
            short8 af[4], bfr[4];
            #pragma unroll
            for (int mi = 0; mi < 4; mi++)
                af[mi] = *(const short8*)(wAp + ((kk * 64 + mi * 16 + lr) * 64 + ks * 32 + kg * 8));
            #pragma unroll
            for (int ti = 0; ti < 4; ti++) {
                const int row = t0w + ti * 16 + lr + kk;
                const int addr = row * 128 + ((ks * 64 + kg * 16) ^ ((row & 7) << 4));
                bfr[ti] = *(const short8*)((const char*)xs + addr);
            }
            #pragma unroll
            for (int ti = 0; ti < 4; ti++)
                #pragma unroll
                for (int mi = 0; mi < 4; mi++)
                    acc[mi][ti] = __builtin_amdgcn_mfma_f32_16x16x32_bf16(af[mi], bfr[ti], acc[mi][ti], 0, 0, 0);
        }
    }
    __syncthreads();

    {
        float cbl[16];
        #pragma unroll
        for (int mi = 0; mi < 4; mi++)
            #pragma unroll
            for (int r = 0; r < 4; r++) cbl[mi * 4 + r] = cb[mi * 16 + kg * 4 + r];
        #pragma unroll
        for (int mi = 0; mi < 4; mi++) {
            #pragma unroll
            for (int ti = 0; ti < 4; ti++) {
                const int t = t0w + ti * 16 + lr;
                short4v yv;
                #pragma unroll
                for (int r = 0; r < 4; r++)
                    yv[r] = bf16bits(fmaxf(acc[mi][ti][r] + cbl[mi * 4 + r], 0.f));
                const int addr = t * 128 + ((mi * 32 + kg * 8) ^ ((t & 7) << 4));
                *(short4v*)((char*)xs + addr) = yv;
            }
        }
    }
    __syncthreads();

    f32x4 acc2[4][4];
    #pragma unroll
    for (int mi = 0; mi < 4; mi++)
        #pragma unroll
        for (int ti = 0; ti < 4; ti++)
            acc2[mi][ti] = (f32x4){0.f, 0.f, 0.f, 0.f};

    const short* gAp = (const short*)gA;
    #pragma unroll
    for (int ks = 0; ks < 2; ks++) {
        short8 af[4], bfr[4];
        #pragma unroll
        for (int mi = 0; mi < 4; mi++)
            af[mi] = *(const short8*)(gAp + ((mi * 16 + lr) * 64 + ks * 32 + kg * 8));
        #pragma unroll
        for (int ti = 0; ti < 4; ti++) {
            const int t = t0w + ti * 16 + lr;
            const int addr = t * 128 + ((ks * 64 + kg * 16) ^ ((t & 7) << 4));
            bfr[ti] = *(const short8*)((const char*)xs + addr);
        }
        #pragma unroll
        for (int ti = 0; ti < 4; ti++)
            #pragma unroll
            for (int mi = 0; mi < 4; mi++)
                acc2[mi][ti] = __builtin_amdgcn_mfma_f32_16x16x32_bf16(af[mi], bfr[ti], acc2[mi][ti], 0, 0, 0);
    }

    #pragma unroll
    for (int mi = 0; mi < 4; mi++) {
        #pragma unroll
        for (int r = 0; r < 4; r++) {
            const int h = mi * 16 + kg * 4 + r;
            bf16* orow = s_out + ((size_t)(lb * 64 + h) * NN + n) * TT + t0w + lr;
            #pragma unroll
            for (int ti = 0; ti < 4; ti++)
                orow[ti * 16] = __float2bfloat16(acc2[mi][ti][r]);
        }
    }
}

// ---------------- kernel 5: mean (from partials) + MLP ----------------
// grid (NN, nb), 64 threads. pf[slot][bh][m]: 4 slots; mean = sum/256.
__global__ __launch_bounds__(64) void k_mlp(
    const float* __restrict__ pf, int nbh,
    const float* __restrict__ w1, const float* __restrict__ b1,
    const float* __restrict__ w2, const float* __restrict__ b2,
    float* __restrict__ out)
{
    __shared__ float mm[64];
    __shared__ float hid[32];
    const int n = blockIdx.x, lb = blockIdx.y, tid = threadIdx.x;

    const size_t stride = (size_t)nbh * NN;
    const size_t idx = (size_t)(lb * 64 + tid) * NN + n;
    float s = pf[idx] + pf[stride + idx] + pf[2 * stride + idx] + pf[3 * stride + idx];
    mm[tid] = s * (1.f / 256.f);
    __syncthreads();
    if (tid < 32) {
        float a = b1[tid];
        #pragma unroll
        for (int c = 0; c < 64; c++) a += mm[c] * w1[c * 32 + tid];
        hid[tid] = fmaxf(a, 0.f);
    }
    __syncthreads();
    if (tid == 0) {
        float a = b2[0];
        #pragma unroll
        for (int j = 0; j < 32; j++) a += hid[j] * w2[j];
        out[lb * NN + n] = a;
    }
}

extern "C" void kernel_launch(void* const* d_in, const int* in_sizes, int n_in,
                              void* d_out, int out_size, void* d_ws, size_t ws_size,
                              hipStream_t stream) {
    const float* x       = (const float*)d_in[0];
    const float* adj     = (const float*)d_in[1];
    const float* conv_w1 = (const float*)d_in[2];
    const float* conv_b1 = (const float*)d_in[3];
    const float* conv_w2 = (const float*)d_in[4];
    const float* conv_b2 = (const float*)d_in[5];
    const float* gcn_w1  = (const float*)d_in[6];
    const float* gcn_b1  = (const float*)d_in[7];
    const float* gcn_w2  = (const float*)d_in[8];
    const float* gcn_b2  = (const float*)d_in[9];
    const float* bn_g1   = (const float*)d_in[10];
    const float* bn_be1  = (const float*)d_in[11];
    const float* bn_m1   = (const float*)d_in[12];
    const float* bn_v1   = (const float*)d_in[13];
    const float* bn_g2   = (const float*)d_in[14];
    const float* bn_be2  = (const float*)d_in[15];
    const float* bn_m2   = (const float*)d_in[16];
    const float* bn_v2   = (const float*)d_in[17];
    const float* out_w1  = (const float*)d_in[18];
    const float* out_b1  = (const float*)d_in[19];
    const float* out_w2  = (const float*)d_in[20];
    const float* out_b2  = (const float*)d_in[21];
    float* out = (float*)d_out;

    const size_t per_b = (size_t)HH * NN * TT;             // 8,192,000 elems/batch
    const size_t reserve = 1 << 20;
    const size_t bytes_per_b_both = per_b * 2 * 2;
    int chunk = (int)((ws_size > reserve ? ws_size - reserve : 0) / bytes_per_b_both);
    if (chunk > BB) chunk = BB;
    if (chunk < 1) chunk = 1;

    char* ws = (char*)d_ws;
    bf16* adjb = (bf16*)ws;                                // 524,288 B
    bf16* wA2  = (bf16*)(ws + 0x80000);                    // 24,576 B
    bf16* gA2  = (bf16*)(ws + 0x80000 + 24576);            // 8,192 B
    bf16* wA1  = (bf16*)(ws + 0x80000 + 32768);            // 4,096 B
    bf16* gA1  = (bf16*)(ws + 0x80000 + 36864);            // 8,192 B
    bf16* bufA = (bf16*)(ws + reserve);
    bf16* bufB = bufA + (size_t)chunk * per_b;

    k_prep_adj<<<1024, 256, 0, stream>>>(adj, adjb);
    k_prep_weights<<<88, 256, 0, stream>>>(conv_w1, gcn_w1, conv_w2, gcn_w2,
                                           wA1, gA1, wA2, gA2);

    for (int b0 = 0; b0 < BB; b0 += chunk) {
        const int nb = (BB - b0) < chunk ? (BB - b0) : chunk;
        float* pf = (float*)bufB;   // bufB is dead during layer-2 adj + mlp

        k_conv_mfma1<<<dim3(NN, nb), 256, 0, stream>>>(
            x + (size_t)b0 * NN * TT * FIN, wA1, gA1, conv_b1, bufA);

        k_adj_mfma<false><<<dim3(8, nb * 64), 256, 0, stream>>>(
            bufA, adjb, gcn_b1, bn_g1, bn_be1, bn_m1, bn_v1, bufB, nullptr);

        k_conv_mfma2<<<dim3(NN, nb), 256, 0, stream>>>(
            bufB, wA2, gA2, conv_b2, bufA);

        k_adj_mfma<true><<<dim3(8, nb * 64), 256, 0, stream>>>(
            bufA, adjb, gcn_b2, bn_g2, bn_be2, bn_m2, bn_v2, nullptr, pf);

        k_mlp<<<dim3(NN, nb), 64, 0, stream>>>(
            pf, nb * 64, out_w1, out_b1, out_w2, out_b2, out + (size_t)b0 * NN);
    }
}

// Round 9
// 744.124 us; speedup vs baseline: 18.8802x; 1.1801x over previous
//
#include <hip/hip_runtime.h>
#include <hip/hip_bf16.h>

// SpatioTemporalGNN: B=16, N=500, T=256, F_IN=8, H=64, K=3, OUT=1
// rev 9: k_adj_mfma was LDS-issue-bound (64 ds_read_u16/wave/kstep B-gather,
// 29.4M bank-conflict cycles). B-tile now staged TRANSPOSED [t 128][k 64]
// with XOR slot swizzle (write scatter + b128 frag reads, same involution
// both sides); 64-k rounds halve barriers. Geometry/epilogues unchanged.
// Other kernels identical to rev 8.

#define BB 16
#define NN 500
#define TT 256
#define FIN 8
#define HH 64

using bf16 = __hip_bfloat16;
typedef __attribute__((ext_vector_type(8))) short short8;
typedef __attribute__((ext_vector_type(4))) short short4v;
typedef __attribute__((ext_vector_type(4))) float f32x4;

static __device__ __forceinline__ short bf16bits(float v) {
    __hip_bfloat16 h = __float2bfloat16(v);
    return *reinterpret_cast<short*>(&h);
}

// ---------------- prep: adj -> padded bf16 [512][512] ----------------
__global__ __launch_bounds__(256) void k_prep_adj(
    const float* __restrict__ adj, bf16* __restrict__ adjb)
{
    int i = blockIdx.x * 256 + threadIdx.x;
    if (i < 512 * 512) {
        int r = i >> 9, c = i & 511;
        float v = (r < NN && c < NN) ? adj[r * NN + c] : 0.f;
        adjb[i] = __float2bfloat16(v);
    }
}

// ---------------- prep: pack all conv/gcn weights to bf16 MFMA-A layouts ----------------
__global__ __launch_bounds__(256) void k_prep_weights(
    const float* __restrict__ cw1, const float* __restrict__ gw1,
    const float* __restrict__ w2,  const float* __restrict__ gw2,
    bf16* __restrict__ wA1, bf16* __restrict__ gA1,
    bf16* __restrict__ wA2, bf16* __restrict__ gA2)
{
    int i = blockIdx.x * 256 + threadIdx.x;
    if (i < 2048) {
        int h = i >> 5, kp = i & 31, kk = kp >> 3, f = kp & 7;
        wA1[i] = __float2bfloat16(kk < 3 ? cw1[(h * 8 + f) * 3 + kk] : 0.f);
    } else if (i < 6144) {
        int j = i - 2048, h = j >> 6, c = j & 63;
        gA1[j] = __float2bfloat16(gw1[c * 64 + h]);
    } else if (i < 18432) {
        int j = i - 6144, kk = j / 4096, r = j & 4095, co = r >> 6, ci = r & 63;
        wA2[j] = __float2bfloat16(w2[(co * 64 + ci) * 3 + kk]);
    } else if (i < 22528) {
        int j = i - 18432, h = j >> 6, c = j & 63;
        gA2[j] = __float2bfloat16(gw2[c * 64 + h]);
    }
}

// ---------------- kernel 1: conv1 + relu + support1 via MFMA ----------------
__global__ __launch_bounds__(256) void k_conv_mfma1(
    const float* __restrict__ x, const bf16* __restrict__ wA1,
    const bf16* __restrict__ gA1, const float* __restrict__ cb,
    bf16* __restrict__ s_out)
{
    __shared__ __align__(16) short xs[256 * 64];   // 32 KB, pitch 128 B, swizzled

    const int tid = threadIdx.x;
    const int n = blockIdx.x, lb = blockIdx.y;
    const int lane = tid & 63, w = tid >> 6;
    const int lr = lane & 15, kg = lane >> 4;
    const int t0w = w * 64;

    {
        const float4* gx = (const float4*)(x + (size_t)(lb * NN + n) * (TT * FIN) + tid * 8);
        float4 a = gx[0], b = gx[1];
        short8 v;
        v[0] = bf16bits(a.x); v[1] = bf16bits(a.y); v[2] = bf16bits(a.z); v[3] = bf16bits(a.w);
        v[4] = bf16bits(b.x); v[5] = bf16bits(b.y); v[6] = bf16bits(b.z); v[7] = bf16bits(b.w);
        const int t = tid;
        *(short8*)((char*)xs + t * 128 + (16 ^ ((t & 7) << 4))) = v;
        if (t < 255)
            *(short8*)((char*)xs + (t + 1) * 128 + (0 ^ (((t + 1) & 7) << 4))) = v;
        if (t > 0)
            *(short8*)((char*)xs + (t - 1) * 128 + (32 ^ (((t - 1) & 7) << 4))) = v;
        short8 z = {0, 0, 0, 0, 0, 0, 0, 0};
        *(short8*)((char*)xs + t * 128 + (48 ^ ((t & 7) << 4))) = z;
        if (t == 0)   *(short8*)((char*)xs + 0 * 128 + (0 ^ 0)) = z;
        if (t == 255) *(short8*)((char*)xs + 255 * 128 + (32 ^ ((255 & 7) << 4))) = z;
    }
    __syncthreads();

    f32x4 acc[4][4];
    #pragma unroll
    for (int mi = 0; mi < 4; mi++)
        #pragma unroll
        for (int ti = 0; ti < 4; ti++)
            acc[mi][ti] = (f32x4){0.f, 0.f, 0.f, 0.f};

    const short* wAp = (const short*)wA1;
    {
        short8 af[4], bfr[4];
        #pragma unroll
        for (int mi = 0; mi < 4; mi++)
            af[mi] = *(const short8*)(wAp + (mi * 16 + lr) * 32 + kg * 8);
        #pragma unroll
        for (int ti = 0; ti < 4; ti++) {
            const int row = t0w + ti * 16 + lr;
            bfr[ti] = *(const short8*)((const char*)xs + row * 128 + ((kg * 16) ^ ((row & 7) << 4)));
        }
        #pragma unroll
        for (int ti = 0; ti < 4; ti++)
            #pragma unroll
            for (int mi = 0; mi < 4; mi++)
                acc[mi][ti] = __builtin_amdgcn_mfma_f32_16x16x32_bf16(af[mi], bfr[ti], acc[mi][ti], 0, 0, 0);
    }
    __syncthreads();

    {
        float cbl[16];
        #pragma unroll
        for (int mi = 0; mi < 4; mi++)
            #pragma unroll
            for (int r = 0; r < 4; r++) cbl[mi * 4 + r] = cb[mi * 16 + kg * 4 + r];
        #pragma unroll
        for (int mi = 0; mi < 4; mi++) {
            #pragma unroll
            for (int ti = 0; ti < 4; ti++) {
                const int t = t0w + ti * 16 + lr;
                short4v yv;
                #pragma unroll
                for (int r = 0; r < 4; r++)
                    yv[r] = bf16bits(fmaxf(acc[mi][ti][r] + cbl[mi * 4 + r], 0.f));
                *(short4v*)((char*)xs + t * 128 + ((mi * 32 + kg * 8) ^ ((t & 7) << 4))) = yv;
            }
        }
    }
    __syncthreads();

    f32x4 acc2[4][4];
    #pragma unroll
    for (int mi = 0; mi < 4; mi++)
        #pragma unroll
        for (int ti = 0; ti < 4; ti++)
            acc2[mi][ti] = (f32x4){0.f, 0.f, 0.f, 0.f};

    const short* gAp = (const short*)gA1;
    #pragma unroll
    for (int ks = 0; ks < 2; ks++) {
        short8 af[4], bfr[4];
        #pragma unroll
        for (int mi = 0; mi < 4; mi++)
            af[mi] = *(const short8*)(gAp + (mi * 16 + lr) * 64 + ks * 32 + kg * 8);
        #pragma unroll
        for (int ti = 0; ti < 4; ti++) {
            const int t = t0w + ti * 16 + lr;
            bfr[ti] = *(const short8*)((const char*)xs + t * 128 + ((ks * 64 + kg * 16) ^ ((t & 7) << 4)));
        }
        #pragma unroll
        for (int ti = 0; ti < 4; ti++)
            #pragma unroll
            for (int mi = 0; mi < 4; mi++)
                acc2[mi][ti] = __builtin_amdgcn_mfma_f32_16x16x32_bf16(af[mi], bfr[ti], acc2[mi][ti], 0, 0, 0);
    }

    #pragma unroll
    for (int mi = 0; mi < 4; mi++) {
        #pragma unroll
        for (int r = 0; r < 4; r++) {
            const int h = mi * 16 + kg * 4 + r;
            bf16* orow = s_out + ((size_t)(lb * 64 + h) * NN + n) * TT + t0w + lr;
            #pragma unroll
            for (int ti = 0; ti < 4; ti++)
                orow[ti * 16] = __float2bfloat16(acc2[mi][ti][r]);
        }
    }
}

// ---------------- kernel 2/4: adj GEMM via MFMA + bias + relu + BN ----------------
// B-tile staged transposed [t 128][k 64] bf16, pitch 128 B, slot swizzle
// slot ^= (t&7) ^ ((t>>5)<<1). B-frag = single ds_read_b128. 64-k rounds.
#define SWZ_T(t) (((((t) & 7) ^ (((t) >> 5) << 1)) & 7) << 4)

template<bool MEAN>
__global__ __launch_bounds__(256) void k_adj_mfma(
    const bf16* __restrict__ s_in, const bf16* __restrict__ adjb,
    const float* __restrict__ gb, const float* __restrict__ bn_g,
    const float* __restrict__ bn_b, const float* __restrict__ bn_m,
    const float* __restrict__ bn_v, bf16* __restrict__ h_out,
    float* __restrict__ pf)
{
    __shared__ __align__(16) short AsS[128 * 72];   // A [m 128][k 64], pitch 72  (18.4 KB)
    __shared__ __align__(16) short BtS[128 * 64];   // B^T [t 128][k 64], swizzled (16 KB)

    const int tid = threadIdx.x;
    const int m0 = (blockIdx.x >> 1) * 128;
    const int t0 = (blockIdx.x & 1) * 128;
    const int bh = blockIdx.y;
    const int h = bh & 63;

    const int lane = tid & 63;
    const int lr = lane & 15;
    const int kg = lane >> 4;
    const int w = tid >> 6;
    const int wr = w >> 1, wc = w & 1;

    f32x4 acc[4][4];
    #pragma unroll
    for (int mi = 0; mi < 4; mi++)
        #pragma unroll
        for (int ti = 0; ti < 4; ti++)
            acc[mi][ti] = (f32x4){0.f, 0.f, 0.f, 0.f};

    // staging maps (constant per thread)
    const int ar = tid >> 1, ah = (tid & 1) * 32;        // A: row, 32-k half
    const int sk = tid >> 2, tseg = (tid & 3) * 32;      // B: k, 32-t segment
    const bf16* sslice = s_in + (size_t)bh * (NN * TT) + t0;

    for (int rnd = 0; rnd < 8; rnd++) {
        const int k0 = rnd * 64;
        // ---- stage A: adjb[m0+ar][k0+ah .. +31] ----
        {
            const float4* src = (const float4*)(adjb + (size_t)(m0 + ar) * 512 + k0 + ah);
            float4* dst = (float4*)(AsS + ar * 72 + ah);
            dst[0] = src[0]; dst[1] = src[1]; dst[2] = src[2]; dst[3] = src[3];
        }
        // ---- stage B transposed: S[k0+sk][t0+tseg .. +31] -> BtS[t][k] swizzled ----
        {
            const int kglob = k0 + sk;
            short8 v0, v1, v2, v3;
            if (kglob < NN) {
                const short8* g = (const short8*)(sslice + (size_t)kglob * TT + tseg);
                v0 = g[0]; v1 = g[1]; v2 = g[2]; v3 = g[3];
            } else {
                v0 = (short8){0,0,0,0,0,0,0,0}; v1 = v0; v2 = v0; v3 = v0;
            }
            const int kslot = (sk >> 3) << 4;     // 16-B slot index of this k
            const int kfine = (sk & 7) * 2;       // byte within slot
            #pragma unroll
            for (int u = 0; u < 4; u++) {
                short8 v = (u == 0) ? v0 : (u == 1) ? v1 : (u == 2) ? v2 : v3;
                #pragma unroll
                for (int j = 0; j < 8; j++) {
                    const int t = tseg + u * 8 + j;
                    *(short*)((char*)BtS + t * 128 + (kslot ^ SWZ_T(t)) + kfine) = v[j];
                }
            }
        }
        __syncthreads();

        #pragma unroll
        for (int ks = 0; ks < 2; ks++) {
            short8 af[4], bfr[4];
            #pragma unroll
            for (int mi = 0; mi < 4; mi++)
                af[mi] = *(const short8*)(AsS + (wr * 64 + mi * 16 + lr) * 72 + ks * 32 + kg * 8);
            #pragma unroll
            for (int ti = 0; ti < 4; ti++) {
                const int t = wc * 64 + ti * 16 + lr;
                bfr[ti] = *(const short8*)((const char*)BtS + t * 128 + ((((ks * 4 + kg) << 4)) ^ SWZ_T(t)));
            }
            #pragma unroll
            for (int ti = 0; ti < 4; ti++)
                #pragma unroll
                for (int mi = 0; mi < 4; mi++)
                    acc[mi][ti] = __builtin_amdgcn_mfma_f32_16x16x32_bf16(af[mi], bfr[ti], acc[mi][ti], 0, 0, 0);
        }
        __syncthreads();
    }

    const float bias  = gb[h];
    const float scale = bn_g[h] / sqrtf(bn_v[h] + 1e-5f);
    const float shift = bn_b[h] - bn_m[h] * scale;

    if constexpr (!MEAN) {
        #pragma unroll
        for (int mi = 0; mi < 4; mi++) {
            const int mbase = m0 + wr * 64 + mi * 16 + kg * 4;
            #pragma unroll
            for (int r = 0; r < 4; r++) {
                const int m = mbase + r;
                if (m < NN) {
                    bf16* orow = h_out + ((size_t)bh * NN + m) * TT + t0 + wc * 64 + lr;
                    #pragma unroll
                    for (int ti = 0; ti < 4; ti++) {
                        float v = fmaxf(acc[mi][ti][r] + bias, 0.f);
                        orow[ti * 16] = __float2bfloat16(v * scale + shift);
                    }
                }
            }
        }
    } else {
        float sums[4][4];
        #pragma unroll
        for (int mi = 0; mi < 4; mi++)
            #pragma unroll
            for (int r = 0; r < 4; r++) {
                float s = 0.f;
                #pragma unroll
                for (int ti = 0; ti < 4; ti++)
                    s += fmaxf(acc[mi][ti][r] + bias, 0.f) * scale + shift;
                sums[mi][r] = s;
            }
        #pragma unroll
        for (int off = 1; off < 16; off <<= 1)
            #pragma unroll
            for (int mi = 0; mi < 4; mi++)
                #pragma unroll
                for (int r = 0; r < 4; r++)
                    sums[mi][r] += __shfl_xor(sums[mi][r], off, 64);
        if (lr == 0) {
            const size_t stride = (size_t)gridDim.y * NN;
            float* pfb = pf + ((size_t)((blockIdx.x & 1) * 2 + wc)) * stride + (size_t)bh * NN;
            #pragma unroll
            for (int mi = 0; mi < 4; mi++) {
                const int m = m0 + wr * 64 + mi * 16 + kg * 4;
                if (m < NN) {
                    float4 v = make_float4(sums[mi][0], sums[mi][1], sums[mi][2], sums[mi][3]);
                    *(float4*)(pfb + m) = v;
                }
            }
        }
    }
}

// ---------------- kernel 3: conv2 + relu + support2 via MFMA ----------------
__global__ __launch_bounds__(256) void k_conv_mfma2(
    const bf16* __restrict__ hin, const bf16* __restrict__ wA,
    const bf16* __restrict__ gA, const float* __restrict__ cb,
    bf16* __restrict__ s_out)
{
    __shared__ __align__(16) short xs[258 * 64];   // 33 KB, swizzled

    const int tid = threadIdx.x;
    const int n = blockIdx.x, lb = blockIdx.y;
    const int lane = tid & 63, w = tid >> 6;
    const int lr = lane & 15, kg = lane >> 4;
    const int t0w = w * 64;

    const bf16* base = hin + ((size_t)lb * 64 * NN + n) * TT;

    {
        const int cin = tid >> 2, tq = (tid & 3) * 64;
        const short* gsrc = (const short*)(base + (size_t)cin * (NN * TT) + tq);
        #pragma unroll
        for (int i = 0; i < 8; i++) {
            short8 v = *(const short8*)(gsrc + i * 8);
            #pragma unroll
            for (int j = 0; j < 8; j++) {
                const int row = tq + i * 8 + j + 1;
                const int addr = row * 128 + ((cin * 2) ^ ((row & 7) << 4));
                *(short*)((char*)xs + addr) = v[j];
            }
        }
        if (tid < 64) {
            *(short*)((char*)xs + (tid * 2)) = 0;
            *(short*)((char*)xs + 257 * 128 + ((tid * 2) ^ 16)) = 0;
        }
    }
    __syncthreads();

    f32x4 acc[4][4];
    #pragma unroll
    for (int mi = 0; mi < 4; mi++)
        #pragma unroll
        for (int ti = 0; ti < 4; ti++)
            acc[mi][ti] = (f32x4){0.f, 0.f, 0.f, 0.f};

    const short* wAp = (const short*)wA;
    #pragma unroll
    for (int kk = 0; kk < 3; kk++) {
        #pragma unroll
        for (int ks = 0; ks < 2; ks++) {
            short8 af[4], bfr[4];
            #pragma unroll
            for (int mi = 0; mi < 4; mi++)
                af[mi] = *(const short8*)(wAp + ((kk * 64 + mi * 16 + lr) * 64 + ks * 32 + kg * 8));
            #pragma unroll
            for (int ti = 0; ti < 4; ti++) {
                const int row = t0w + ti * 16 + lr + kk;
                const int addr = row * 128 + ((ks * 64 + kg * 16) ^ ((row & 7) << 4));
                bfr[ti] = *(const short8*)((const char*)xs + addr);
            }
            #pragma unroll
            for (int ti = 0; ti < 4; ti++)
                #pragma unroll
                for (int mi = 0; mi < 4; mi++)
                    acc[mi][ti] = __builtin_amdgcn_mfma_f32_16x16x32_bf16(af[mi], bfr[ti], acc[mi][ti], 0, 0, 0);
        }
    }
    __syncthreads();

    {
        float cbl[16];
        #pragma unroll
        for (int mi = 0; mi < 4; mi++)
            #pragma unroll
            for (int r = 0; r < 4; r++) cbl[mi * 4 + r] = cb[mi * 16 + kg * 4 + r];
        #pragma unroll
        for (int mi = 0; mi < 4; mi++) {
            #pragma unroll
            for (int ti = 0; ti < 4; ti++) {
                const int t = t0w + ti * 16 + lr;
                short4v yv;
                #pragma unroll
                for (int r = 0; r < 4; r++)
                    yv[r] = bf16bits(fmaxf(acc[mi][ti][r] + cbl[mi * 4 + r], 0.f));
                const int addr = t * 128 + ((mi * 32 + kg * 8) ^ ((t & 7) << 4));
                *(short4v*)((char*)xs + addr) = yv;
            }
        }
    }
    __syncthreads();

    f32x4 acc2[4][4];
    #pragma unroll
    for (int mi = 0; mi < 4; mi++)
        #pragma unroll
        for (int ti = 0; ti < 4; ti++)
            acc2[mi][ti] = (f32x4){0.f, 0.f, 0.f, 0.f};

    const short* gAp = (const short*)gA;
    #pragma unroll
    for (int ks = 0; ks < 2; ks++) {
        short8 af[4], bfr[4];
        #pragma unroll
        for (int mi = 0; mi < 4; mi++)
            af[mi] = *(const short8*)(gAp + ((mi * 16 + lr) * 64 + ks * 32 + kg * 8));
        #pragma unroll
        for (int ti = 0; ti < 4; ti++) {
            const int t = t0w + ti * 16 + lr;
            const int addr = t * 128 + ((ks * 64 + kg * 16) ^ ((t & 7) << 4));
            bfr[ti] = *(const short8*)((const char*)xs + addr);
        }
        #pragma unroll
        for (int ti = 0; ti < 4; ti++)
            #pragma unroll
            for (int mi = 0; mi < 4; mi++)
                acc2[mi][ti] = __builtin_amdgcn_mfma_f32_16x16x32_bf16(af[mi], bfr[ti], acc2[mi][ti], 0, 0, 0);
    }

    #pragma unroll
    for (int mi = 0; mi < 4; mi++) {
        #pragma unroll
        for (int r = 0; r < 4; r++) {
            const int h = mi * 16 + kg * 4 + r;
            bf16* orow = s_out + ((size_t)(lb * 64 + h) * NN + n) * TT + t0w + lr;
            #pragma unroll
            for (int ti = 0; ti < 4; ti++)
                orow[ti * 16] = __float2bfloat16(acc2[mi][ti][r]);
        }
    }
}

// ---------------- kernel 5: mean (from partials) + MLP ----------------
__global__ __launch_bounds__(64) void k_mlp(
    const float* __restrict__ pf, int nbh,
    const float* __restrict__ w1, const float* __restrict__ b1,
    const float* __restrict__ w2, const float* __restrict__ b2,
    float* __restrict__ out)
{
    __shared__ float mm[64];
    __shared__ float hid[32];
    const int n = blockIdx.x, lb = blockIdx.y, tid = threadIdx.x;

    const size_t stride = (size_t)nbh * NN;
    const size_t idx = (size_t)(lb * 64 + tid) * NN + n;
    float s = pf[idx] + pf[stride + idx] + pf[2 * stride + idx] + pf[3 * stride + idx];
    mm[tid] = s * (1.f / 256.f);
    __syncthreads();
    if (tid < 32) {
        float a = b1[tid];
        #pragma unroll
        for (int c = 0; c < 64; c++) a += mm[c] * w1[c * 32 + tid];
        hid[tid] = fmaxf(a, 0.f);
    }
    __syncthreads();
    if (tid == 0) {
        float a = b2[0];
        #pragma unroll
        for (int j = 0; j < 32; j++) a += hid[j] * w2[j];
        out[lb * NN + n] = a;
    }
}

extern "C" void kernel_launch(void* const* d_in, const int* in_sizes, int n_in,
                              void* d_out, int out_size, void* d_ws, size_t ws_size,
                              hipStream_t stream) {
    const float* x       = (const float*)d_in[0];
    const float* adj     = (const float*)d_in[1];
    const float* conv_w1 = (const float*)d_in[2];
    const float* conv_b1 = (const float*)d_in[3];
    const float* conv_w2 = (const float*)d_in[4];
    const float* conv_b2 = (const float*)d_in[5];
    const float* gcn_w1  = (const float*)d_in[6];
    const float* gcn_b1  = (const float*)d_in[7];
    const float* gcn_w2  = (const float*)d_in[8];
    const float* gcn_b2  = (const float*)d_in[9];
    const float* bn_g1   = (const float*)d_in[10];
    const float* bn_be1  = (const float*)d_in[11];
    const float* bn_m1   = (const float*)d_in[12];
    const float* bn_v1   = (const float*)d_in[13];
    const float* bn_g2   = (const float*)d_in[14];
    const float* bn_be2  = (const float*)d_in[15];
    const float* bn_m2   = (const float*)d_in[16];
    const float* bn_v2   = (const float*)d_in[17];
    const float* out_w1  = (const float*)d_in[18];
    const float* out_b1  = (const float*)d_in[19];
    const float* out_w2  = (const float*)d_in[20];
    const float* out_b2  = (const float*)d_in[21];
    float* out = (float*)d_out;

    const size_t per_b = (size_t)HH * NN * TT;             // 8,192,000 elems/batch
    const size_t reserve = 1 << 20;
    const size_t bytes_per_b_both = per_b * 2 * 2;
    int chunk = (int)((ws_size > reserve ? ws_size - reserve : 0) / bytes_per_b_both);
    if (chunk > BB) chunk = BB;
    if (chunk < 1) chunk = 1;

    char* ws = (char*)d_ws;
    bf16* adjb = (bf16*)ws;                                // 524,288 B
    bf16* wA2  = (bf16*)(ws + 0x80000);                    // 24,576 B
    bf16* gA2  = (bf16*)(ws + 0x80000 + 24576);            // 8,192 B
    bf16* wA1  = (bf16*)(ws + 0x80000 + 32768);            // 4,096 B
    bf16* gA1  = (bf16*)(ws + 0x80000 + 36864);            // 8,192 B
    bf16* bufA = (bf16*)(ws + reserve);
    bf16* bufB = bufA + (size_t)chunk * per_b;

    k_prep_adj<<<1024, 256, 0, stream>>>(adj, adjb);
    k_prep_weights<<<88, 256, 0, stream>>>(conv_w1, gcn_w1, conv_w2, gcn_w2,
                                           wA1, gA1, wA2, gA2);

    for (int b0 = 0; b0 < BB; b0 += chunk) {
        const int nb = (BB - b0) < chunk ? (BB - b0) : chunk;
        float* pf = (float*)bufB;   // bufB is dead during layer-2 adj + mlp

        k_conv_mfma1<<<dim3(NN, nb), 256, 0, stream>>>(
            x + (size_t)b0 * NN * TT * FIN, wA1, gA1, conv_b1, bufA);

        k_adj_mfma<false><<<dim3(8, nb * 64), 256, 0, stream>>>(
            bufA, adjb, gcn_b1, bn_g1, bn_be1, bn_m1, bn_v1, bufB, nullptr);

        k_conv_mfma2<<<dim3(NN, nb), 256, 0, stream>>>(
            bufB, wA2, gA2, conv_b2, bufA);

        k_adj_mfma<true><<<dim3(8, nb * 64), 256, 0, stream>>>(
            bufA, adjb, gcn_b2, bn_g2, bn_be2, bn_m2, bn_v2, nullptr, pf);

        k_mlp<<<dim3(NN, nb), 64, 0, stream>>>(
            pf, nb * 64, out_w1, out_b1, out_w2, out_b2, out + (size_t)b0 * NN);
    }
}